// Round 6
// baseline (600.471 us; speedup 1.0000x reference)
//
#include <hip/hip_runtime.h>
#include <hip/hip_bf16.h>

typedef unsigned short u16;
typedef __bf16 bf16x8 __attribute__((ext_vector_type(8)));
typedef float f32x4 __attribute__((ext_vector_type(4)));
typedef unsigned short u16x8 __attribute__((ext_vector_type(8)));

// ---------- helpers ----------
__device__ __forceinline__ void async_copy16(void* lds, const void* g) {
  __builtin_amdgcn_global_load_lds(
      (const __attribute__((address_space(1))) unsigned int*)g,
      (__attribute__((address_space(3))) unsigned int*)lds, 16, 0, 0);
}

__device__ __forceinline__ u16 f2bf(float f) {
  __hip_bfloat16 h = __float2bfloat16(f);
  u16 u;
  __builtin_memcpy(&u, &h, 2);
  return u;
}

// RNE float->bf16 without NaN handling (inputs known finite): 3 VALU ops.
__device__ __forceinline__ u16 f2bf_rne(float f) {
  unsigned b = __builtin_bit_cast(unsigned, f);
  b += 0x7FFF + ((b >> 16) & 1);
  return (u16)(b >> 16);
}

// ---------- f32 -> bf16 convert (vectorized) ----------
__global__ void k_f32_to_bf16(const float* __restrict__ in, u16* __restrict__ out, int n4) {
  int i = blockIdx.x * blockDim.x + threadIdx.x;
  if (i >= n4) return;
  float4 v = ((const float4*)in)[i];
  ushort4 o;
  o.x = f2bf(v.x); o.y = f2bf(v.y); o.z = f2bf(v.z); o.w = f2bf(v.w);
  ((ushort4*)out)[i] = o;
}

// ---------- transpose RxC f32 -> CxR bf16 ----------
__global__ void k_transpose_bf16(const float* __restrict__ in, u16* __restrict__ out, int R, int C) {
  __shared__ float tile[32][33];
  int bx = blockIdx.x * 32;
  int by = blockIdx.y * 32;
  int tx = threadIdx.x & 31, ty = threadIdx.x >> 5;
  for (int i = ty; i < 32; i += 8) tile[i][tx] = in[(size_t)(by + i) * C + bx + tx];
  __syncthreads();
  for (int i = ty; i < 32; i += 8) out[(size_t)(bx + i) * R + by + tx] = f2bf(tile[tx][i]);
}

// ---------- GEMM: C(MxN) = A(MxK,bf16) @ Bt(NxK,bf16)^T + bias ----------
template <int OUT_BF16>
__global__ __launch_bounds__(256, 2) void k_gemm_bt(
    const u16* __restrict__ A, const u16* __restrict__ Bt,
    const float* __restrict__ bias, void* __restrict__ Cout,
    int M, int N, int K) {
  __shared__ __align__(16) u16 As[128][32];
  __shared__ __align__(16) u16 Bs[128][32];
  const int t = threadIdx.x;
  const int l = t & 63, w = t >> 6;
  const int lr = l & 15, lk = l >> 4;
  const int wr = w >> 1, wc = w & 1;
  const int m0 = blockIdx.x * 128, n0 = blockIdx.y * 128;

  f32x4 acc[4][4] = {};

  for (int k0 = 0; k0 < K; k0 += 32) {
    __syncthreads();
    for (int c = 0; c < 2; ++c) {
      int idx = c * 256 + t;
      int row = idx >> 2, slot = idx & 3;
      int sw = (slot ^ ((row >> 1) & 3)) << 3;
      async_copy16((char*)&As[0][0] + idx * 16, A + (size_t)(m0 + row) * K + k0 + sw);
      async_copy16((char*)&Bs[0][0] + idx * 16, Bt + (size_t)(n0 + row) * K + k0 + sw);
    }
    __syncthreads();
    bf16x8 af[4], bfr[4];
    for (int m = 0; m < 4; ++m) {
      int row = wr * 64 + m * 16 + lr;
      af[m] = *(const bf16x8*)((const char*)&As[0][0] + row * 64 + ((lk ^ ((row >> 1) & 3)) << 4));
    }
    for (int n = 0; n < 4; ++n) {
      int row = wc * 64 + n * 16 + lr;
      bfr[n] = *(const bf16x8*)((const char*)&Bs[0][0] + row * 64 + ((lk ^ ((row >> 1) & 3)) << 4));
    }
    for (int m = 0; m < 4; ++m)
      for (int n = 0; n < 4; ++n)
        acc[m][n] = __builtin_amdgcn_mfma_f32_16x16x32_bf16(af[m], bfr[n], acc[m][n], 0, 0, 0);
  }

  for (int n = 0; n < 4; ++n) {
    int col = n0 + wc * 64 + n * 16 + lr;
    float bv = bias[col];
    for (int m = 0; m < 4; ++m) {
      int rowb = m0 + wr * 64 + m * 16 + lk * 4;
      for (int r = 0; r < 4; ++r) {
        float v = acc[m][n][r] + bv;
        size_t off = (size_t)(rowb + r) * N + col;
        if constexpr (OUT_BF16) ((u16*)Cout)[off] = f2bf(v);
        else ((float*)Cout)[off] = v;
      }
    }
  }
}

// ---------- flash attention, causal, bf16 ----------
// grid (B*H, 16); block 256 = 4 waves x 16 q-rows per q-tile. Block (bh, p)
// handles 64-row q-tiles p (A) and 31-p (B) -> 33 uniform KV-tile-units.
// LDS = 40960 B exactly -> 4 blocks/CU. R5 lesson: true per-wave reg use
// (arch 112 + acc) was ~176 -> only 2 waves/SIMD resident (occ 21%).
// Fix: B-then-A SEQUENTIAL QK (one s[4] live at a time, ~116-reg peak) +
// __launch_bounds__(256,4) to fit 4 waves/SIMD. Spill tripwire: FETCH_SIZE
// must stay ~36 MB (R4 spill signature was 950 MB).
__global__ __launch_bounds__(256, 4) void k_attn(
    const u16* __restrict__ QKV,  // (B*S) x 3072 bf16: [Q|K|V]
    u16* __restrict__ O) {        // (B*S) x 1024 bf16
  const int bh = blockIdx.x;  // 0..63 (fastest; bh%8 pins each bh-stream to one XCD)
  const int p = blockIdx.y;   // 0..15
  const int b = bh >> 4, h = bh & 15;
  const int t = threadIdx.x;
  const int l = t & 63, w = t >> 6;  // 4 waves
  const int lr = l & 15, lk = l >> 4;
  constexpr float LG = 0.18033688f;  // 0.125 * log2(e)

  __shared__ __align__(16) u16 Ks[2][64][64];  // key tiles (src-swizzled), dbuf: 16 KB
  __shared__ __align__(16) u16 VT[2][64][64];  // V^T tiles (two-sided swizzle), dbuf: 16 KB
  __shared__ __align__(16) u16 Pl[4][16][64];  // per-wave P, XOR-swizzled (chunk^=row&7): 8 KB

  const int qtA = p, qtB = 31 - p;
  const int ntA = qtA + 1, ntB = qtB + 1;  // sum = 33
  const int q0A = qtA * 64 + w * 16, q0B = qtB * 64 + w * 16;
  const size_t rowQA = (size_t)b * 2048 + q0A;
  const size_t rowQB = (size_t)b * 2048 + q0B;

  bf16x8 qfA[2], qfB[2];
#pragma unroll
  for (int c = 0; c < 2; ++c) {
    qfA[c] = *(const bf16x8*)(QKV + (rowQA + lr) * 3072 + h * 64 + c * 32 + lk * 8);
    qfB[c] = *(const bf16x8*)(QKV + (rowQB + lr) * 3072 + h * 64 + c * 32 + lk * 8);
  }

  f32x4 accA[4] = {}, accB[4] = {};
  float miA[4], liA[4], miB[4], liB[4];
#pragma unroll
  for (int r = 0; r < 4; ++r) {
    miA[r] = -__builtin_inff(); liA[r] = 0.f;
    miB[r] = -__builtin_inff(); liB[r] = 0.f;
  }

  const u16* Kb0 = QKV + (size_t)b * 2048 * 3072 + 1024 + h * 64;
  const u16* Vb0 = Kb0 + 1024;
  u16x8 vreg[2];

  auto stageK = [&](int j, int buf) {
#pragma unroll
    for (int c = 0; c < 2; ++c) {
      int gi = c * 256 + t;
      int row = gi >> 3, slot = gi & 7;
      async_copy16((char*)&Ks[buf][0][0] + gi * 16,
                   Kb0 + ((size_t)j * 64 + row) * 3072 + ((slot ^ (row & 7)) << 3));
    }
  };
  auto loadV = [&](int j) {
#pragma unroll
    for (int c = 0; c < 2; ++c) {
      int r = c * 32 + (t >> 3), dh0 = (t & 7) << 3;
      vreg[c] = *(const u16x8*)(Vb0 + ((size_t)j * 64 + r) * 3072 + dh0);
    }
  };
  auto writeV = [&](int buf) {
#pragma unroll
    for (int c = 0; c < 2; ++c) {
      int r = c * 32 + (t >> 3), dh0 = (t & 7) << 3;
#pragma unroll
      for (int jj = 0; jj < 8; ++jj) {
        int dh = dh0 + jj;
        int phi = (dh & 7) ^ ((dh >> 3) & 7);
        VT[buf][dh][((((r >> 3) ^ phi) & 7) << 3) | (r & 7)] = vreg[c][jj];
      }
    }
  };

  // QK^T for one q-tile (16 rows) from Ks[cur]
  auto qk_one = [&](const bf16x8 (&qf)[2], f32x4 (&s)[4], int cur) {
#pragma unroll
    for (int c = 0; c < 2; ++c)
#pragma unroll
      for (int n = 0; n < 4; ++n) {
        int row = n * 16 + lr;
        bf16x8 kf = *(const bf16x8*)((const char*)&Ks[cur][0][0] + row * 128 +
                                     ((((c * 4 + lk) ^ (row & 7)) & 7) << 4));
        s[n] = __builtin_amdgcn_mfma_f32_16x16x32_bf16(qf[c], kf, s[n], 0, 0, 0);
      }
  };

  // softmax for one 16-row q-tile; writes P (bf16) into Pl[w] swizzled
  auto softmax = [&](f32x4 (&s)[4], float (&mi)[4], float (&li)[4], f32x4 (&acc)[4],
                     int q0w, int j) {
    if (j * 64 + 63 > q0w) {  // wave-uniform mask skip
#pragma unroll
      for (int n = 0; n < 4; ++n)
#pragma unroll
        for (int r = 0; r < 4; ++r)
          if (j * 64 + n * 16 + lr > q0w + lk * 4 + r) s[n][r] = -__builtin_inff();
    }
    float tm[4];
#pragma unroll
    for (int r = 0; r < 4; ++r) {
      float x = fmaxf(fmaxf(s[0][r], s[1][r]), fmaxf(s[2][r], s[3][r]));
      x = fmaxf(x, __shfl_xor(x, 1));
      x = fmaxf(x, __shfl_xor(x, 2));
      x = fmaxf(x, __shfl_xor(x, 4));
      x = fmaxf(x, __shfl_xor(x, 8));
      tm[r] = x;
    }
    bool need = false;
#pragma unroll
    for (int r = 0; r < 4; ++r) need |= (tm[r] > mi[r] + 64.0f);  // defer-max, raw units
    if (__any(need)) {
#pragma unroll
      for (int r = 0; r < 4; ++r) {
        float mnew = fmaxf(mi[r], tm[r]);
        float alpha = __builtin_amdgcn_exp2f((mi[r] - mnew) * LG);
        mi[r] = mnew;
        li[r] *= alpha;
#pragma unroll
        for (int n = 0; n < 4; ++n) acc[n][r] *= alpha;
      }
    }
    u16* pw = &Pl[w][0][0];
#pragma unroll
    for (int r = 0; r < 4; ++r) {
      int row = lk * 4 + r;
      float mc = -mi[r] * LG;
      float ps = 0.f;
#pragma unroll
      for (int n = 0; n < 4; ++n) {
        float pv = __builtin_amdgcn_exp2f(fmaf(s[n][r], LG, mc));
        ps += pv;
        pw[row * 64 + (((n * 2 + (lr >> 3)) ^ (row & 7)) << 3) + (lr & 7)] = f2bf_rne(pv);
      }
      ps += __shfl_xor(ps, 1);
      ps += __shfl_xor(ps, 2);
      ps += __shfl_xor(ps, 4);
      ps += __shfl_xor(ps, 8);
      li[r] += ps;
    }
  };

  // PV: O += P @ V for the tile currently in Pl[w]
  auto pv = [&](f32x4 (&acc)[4], int cur) {
    const u16* pw = &Pl[w][0][0];
#pragma unroll
    for (int c = 0; c < 2; ++c) {
      bf16x8 pa = *(const bf16x8*)(pw + lr * 64 + (((c * 4 + lk) ^ (lr & 7)) << 3));
#pragma unroll
      for (int n = 0; n < 4; ++n) {
        int dh = n * 16 + lr;
        int phi = (dh & 7) ^ ((dh >> 3) & 7);
        bf16x8 vf = *(const bf16x8*)((const char*)&VT[cur][0][0] + dh * 128 +
                                     ((((c * 4 + lk) ^ phi) & 7) << 4));
        acc[n] = __builtin_amdgcn_mfma_f32_16x16x32_bf16(pa, vf, acc[n], 0, 0, 0);
      }
    }
  };

  // prologue: tile 0 into buffer 0
  stageK(0, 0);
  loadV(0);
  writeV(0);
  __syncthreads();

  for (int j = 0; j < ntB; ++j) {
    const int cur = j & 1;
    const bool more = (j + 1 < ntB);
    if (more) { stageK(j + 1, cur ^ 1); loadV(j + 1); }
    const bool doA = (j < ntA);

    // ---- B side (s live only through this span) ----
    {
      f32x4 s[4] = {};
      qk_one(qfB, s, cur);
      softmax(s, miB, liB, accB, q0B, j);
      pv(accB, cur);
    }
    // ---- A side (Pl WAR ordered by in-order DS ops within each wave) ----
    if (doA) {
      f32x4 s[4] = {};
      qk_one(qfA, s, cur);
      softmax(s, miA, liA, accA, q0A, j);
      pv(accA, cur);
    }

    if (more) writeV(cur ^ 1);
    __syncthreads();
  }

  // ---- epilogue: O = acc / l ----
#pragma unroll
  for (int r = 0; r < 4; ++r) {
    float invB = 1.0f / liB[r];
    size_t orowB = (rowQB + lk * 4 + r) * 1024 + h * 64;
#pragma unroll
    for (int n = 0; n < 4; ++n) O[orowB + n * 16 + lr] = f2bf_rne(accB[n][r] * invB);
    float invA = 1.0f / liA[r];
    size_t orowA = (rowQA + lk * 4 + r) * 1024 + h * 64;
#pragma unroll
    for (int n = 0; n < 4; ++n) O[orowA + n * 16 + lr] = f2bf_rne(accA[n][r] * invA);
  }
}

// ---------- launch ----------
extern "C" void kernel_launch(void* const* d_in, const int* in_sizes, int n_in,
                              void* d_out, int out_size, void* d_ws, size_t ws_size,
                              hipStream_t stream) {
  const float* x = (const float*)d_in[0];
  const float* w_qkv = (const float*)d_in[1];
  const float* b_qkv = (const float*)d_in[2];
  const float* w_out = (const float*)d_in[3];
  const float* b_out = (const float*)d_in[4];
  // d_in[5] = mask: always causal tril, handled analytically.

  char* ws = (char*)d_ws;
  u16* X16 = (u16*)(ws);                  // 16 MB; reused as O16 after GEMM1
  u16* WqkvT = (u16*)(ws + 16777216);     // 6 MB
  u16* WoutT = (u16*)(ws + 23068672);     // 2 MB
  u16* QKVb = (u16*)(ws + 25165824);      // 48 MB
  u16* O16 = X16;

  k_f32_to_bf16<<<8192, 256, 0, stream>>>(x, X16, 8388608 / 4);
  k_transpose_bf16<<<dim3(96, 32), 256, 0, stream>>>(w_qkv, WqkvT, 1024, 3072);
  k_transpose_bf16<<<dim3(32, 32), 256, 0, stream>>>(w_out, WoutT, 1024, 1024);
  k_gemm_bt<1><<<dim3(64, 24), 256, 0, stream>>>(X16, WqkvT, b_qkv, QKVb, 8192, 3072, 1024);
  k_attn<<<dim3(64, 16), 256, 0, stream>>>(QKVb, O16);
  k_gemm_bt<0><<<dim3(64, 8), 256, 0, stream>>>(O16, WoutT, b_out, d_out, 8192, 1024, 1024);
}

// Round 7
// 443.385 us; speedup vs baseline: 1.3543x; 1.3543x over previous
//
#include <hip/hip_runtime.h>
#include <hip/hip_bf16.h>

typedef unsigned short u16;
typedef __bf16 bf16x8 __attribute__((ext_vector_type(8)));
typedef float f32x4 __attribute__((ext_vector_type(4)));
typedef unsigned short u16x8 __attribute__((ext_vector_type(8)));

// ---------- helpers ----------
__device__ __forceinline__ void async_copy16(void* lds, const void* g) {
  __builtin_amdgcn_global_load_lds(
      (const __attribute__((address_space(1))) unsigned int*)g,
      (__attribute__((address_space(3))) unsigned int*)lds, 16, 0, 0);
}

__device__ __forceinline__ u16 f2bf(float f) {
  __hip_bfloat16 h = __float2bfloat16(f);
  u16 u;
  __builtin_memcpy(&u, &h, 2);
  return u;
}

// RNE float->bf16 without NaN handling (inputs known finite): 3 VALU ops.
__device__ __forceinline__ u16 f2bf_rne(float f) {
  unsigned b = __builtin_bit_cast(unsigned, f);
  b += 0x7FFF + ((b >> 16) & 1);
  return (u16)(b >> 16);
}

// ---------- f32 -> bf16 convert (vectorized) ----------
__global__ void k_f32_to_bf16(const float* __restrict__ in, u16* __restrict__ out, int n4) {
  int i = blockIdx.x * blockDim.x + threadIdx.x;
  if (i >= n4) return;
  float4 v = ((const float4*)in)[i];
  ushort4 o;
  o.x = f2bf(v.x); o.y = f2bf(v.y); o.z = f2bf(v.z); o.w = f2bf(v.w);
  ((ushort4*)out)[i] = o;
}

// ---------- transpose RxC f32 -> CxR bf16 ----------
__global__ void k_transpose_bf16(const float* __restrict__ in, u16* __restrict__ out, int R, int C) {
  __shared__ float tile[32][33];
  int bx = blockIdx.x * 32;
  int by = blockIdx.y * 32;
  int tx = threadIdx.x & 31, ty = threadIdx.x >> 5;
  for (int i = ty; i < 32; i += 8) tile[i][tx] = in[(size_t)(by + i) * C + bx + tx];
  __syncthreads();
  for (int i = ty; i < 32; i += 8) out[(size_t)(bx + i) * R + by + tx] = f2bf(tile[tx][i]);
}

// ---------- GEMM: C(MxN) = A(MxK,bf16) @ Bt(NxK,bf16)^T + bias ----------
template <int OUT_BF16>
__global__ __launch_bounds__(256, 2) void k_gemm_bt(
    const u16* __restrict__ A, const u16* __restrict__ Bt,
    const float* __restrict__ bias, void* __restrict__ Cout,
    int M, int N, int K) {
  __shared__ __align__(16) u16 As[128][32];
  __shared__ __align__(16) u16 Bs[128][32];
  const int t = threadIdx.x;
  const int l = t & 63, w = t >> 6;
  const int lr = l & 15, lk = l >> 4;
  const int wr = w >> 1, wc = w & 1;
  const int m0 = blockIdx.x * 128, n0 = blockIdx.y * 128;

  f32x4 acc[4][4] = {};

  for (int k0 = 0; k0 < K; k0 += 32) {
    __syncthreads();
    for (int c = 0; c < 2; ++c) {
      int idx = c * 256 + t;
      int row = idx >> 2, slot = idx & 3;
      int sw = (slot ^ ((row >> 1) & 3)) << 3;
      async_copy16((char*)&As[0][0] + idx * 16, A + (size_t)(m0 + row) * K + k0 + sw);
      async_copy16((char*)&Bs[0][0] + idx * 16, Bt + (size_t)(n0 + row) * K + k0 + sw);
    }
    __syncthreads();
    bf16x8 af[4], bfr[4];
    for (int m = 0; m < 4; ++m) {
      int row = wr * 64 + m * 16 + lr;
      af[m] = *(const bf16x8*)((const char*)&As[0][0] + row * 64 + ((lk ^ ((row >> 1) & 3)) << 4));
    }
    for (int n = 0; n < 4; ++n) {
      int row = wc * 64 + n * 16 + lr;
      bfr[n] = *(const bf16x8*)((const char*)&Bs[0][0] + row * 64 + ((lk ^ ((row >> 1) & 3)) << 4));
    }
    for (int m = 0; m < 4; ++m)
      for (int n = 0; n < 4; ++n)
        acc[m][n] = __builtin_amdgcn_mfma_f32_16x16x32_bf16(af[m], bfr[n], acc[m][n], 0, 0, 0);
  }

  for (int n = 0; n < 4; ++n) {
    int col = n0 + wc * 64 + n * 16 + lr;
    float bv = bias[col];
    for (int m = 0; m < 4; ++m) {
      int rowb = m0 + wr * 64 + m * 16 + lk * 4;
      for (int r = 0; r < 4; ++r) {
        float v = acc[m][n][r] + bv;
        size_t off = (size_t)(rowb + r) * N + col;
        if constexpr (OUT_BF16) ((u16*)Cout)[off] = f2bf(v);
        else ((float*)Cout)[off] = v;
      }
    }
  }
}

// ---------- flash attention, causal, bf16 ----------
// grid (B*H, 16); block 256 = 4 waves x 16 q-rows per q-tile. Block (bh, p)
// handles 64-row q-tiles p (A) and 31-p (B) -> 33 uniform KV-tile-units.
// LDS = 40960 B exactly. Register history: natural use ~176 total/wave
// (R5: 112 arch + acc, occ 21% = 2 waves/SIMD); min-waves=4 (128 budget)
// spills catastrophically (R4/R6: FETCH ~1 GB). min-waves=3 (168-170 budget)
// asks the allocator to shave only ~6 regs -> 3 waves/SIMD, 12 waves/CU.
// Spill tripwire: FETCH_SIZE must stay < 100 MB.
__global__ __launch_bounds__(256, 3) void k_attn(
    const u16* __restrict__ QKV,  // (B*S) x 3072 bf16: [Q|K|V]
    u16* __restrict__ O) {        // (B*S) x 1024 bf16
  const int bh = blockIdx.x;  // 0..63 (fastest; bh%8 pins each bh-stream to one XCD)
  const int p = blockIdx.y;   // 0..15
  const int b = bh >> 4, h = bh & 15;
  const int t = threadIdx.x;
  const int l = t & 63, w = t >> 6;  // 4 waves
  const int lr = l & 15, lk = l >> 4;
  constexpr float LG = 0.18033688f;  // 0.125 * log2(e)

  __shared__ __align__(16) u16 Ks[2][64][64];  // key tiles (src-swizzled), dbuf: 16 KB
  __shared__ __align__(16) u16 VT[2][64][64];  // V^T tiles (two-sided swizzle), dbuf: 16 KB
  __shared__ __align__(16) u16 Pl[4][16][64];  // per-wave P, XOR-swizzled (chunk^=row&7): 8 KB

  const int qtA = p, qtB = 31 - p;
  const int ntA = qtA + 1, ntB = qtB + 1;  // sum = 33
  const int q0A = qtA * 64 + w * 16, q0B = qtB * 64 + w * 16;
  const size_t rowQA = (size_t)b * 2048 + q0A;
  const size_t rowQB = (size_t)b * 2048 + q0B;

  bf16x8 qfA[2], qfB[2];
#pragma unroll
  for (int c = 0; c < 2; ++c) {
    qfA[c] = *(const bf16x8*)(QKV + (rowQA + lr) * 3072 + h * 64 + c * 32 + lk * 8);
    qfB[c] = *(const bf16x8*)(QKV + (rowQB + lr) * 3072 + h * 64 + c * 32 + lk * 8);
  }

  f32x4 accA[4] = {}, accB[4] = {};
  float miA[4], liA[4], miB[4], liB[4];
#pragma unroll
  for (int r = 0; r < 4; ++r) {
    miA[r] = -__builtin_inff(); liA[r] = 0.f;
    miB[r] = -__builtin_inff(); liB[r] = 0.f;
  }

  const u16* Kb0 = QKV + (size_t)b * 2048 * 3072 + 1024 + h * 64;
  const u16* Vb0 = Kb0 + 1024;
  u16x8 vreg[2];

  auto stageK = [&](int j, int buf) {
#pragma unroll
    for (int c = 0; c < 2; ++c) {
      int gi = c * 256 + t;
      int row = gi >> 3, slot = gi & 7;
      async_copy16((char*)&Ks[buf][0][0] + gi * 16,
                   Kb0 + ((size_t)j * 64 + row) * 3072 + ((slot ^ (row & 7)) << 3));
    }
  };
  auto loadV = [&](int j) {
#pragma unroll
    for (int c = 0; c < 2; ++c) {
      int r = c * 32 + (t >> 3), dh0 = (t & 7) << 3;
      vreg[c] = *(const u16x8*)(Vb0 + ((size_t)j * 64 + r) * 3072 + dh0);
    }
  };
  auto writeV = [&](int buf) {
#pragma unroll
    for (int c = 0; c < 2; ++c) {
      int r = c * 32 + (t >> 3), dh0 = (t & 7) << 3;
#pragma unroll
      for (int jj = 0; jj < 8; ++jj) {
        int dh = dh0 + jj;
        int phi = (dh & 7) ^ ((dh >> 3) & 7);
        VT[buf][dh][((((r >> 3) ^ phi) & 7) << 3) | (r & 7)] = vreg[c][jj];
      }
    }
  };

  // QK^T for one q-tile (16 rows) from Ks[cur]
  auto qk_one = [&](const bf16x8 (&qf)[2], f32x4 (&s)[4], int cur) {
#pragma unroll
    for (int c = 0; c < 2; ++c)
#pragma unroll
      for (int n = 0; n < 4; ++n) {
        int row = n * 16 + lr;
        bf16x8 kf = *(const bf16x8*)((const char*)&Ks[cur][0][0] + row * 128 +
                                     ((((c * 4 + lk) ^ (row & 7)) & 7) << 4));
        s[n] = __builtin_amdgcn_mfma_f32_16x16x32_bf16(qf[c], kf, s[n], 0, 0, 0);
      }
  };

  // softmax for one 16-row q-tile; writes P (bf16) into Pl[w] swizzled
  auto softmax = [&](f32x4 (&s)[4], float (&mi)[4], float (&li)[4], f32x4 (&acc)[4],
                     int q0w, int j) {
    if (j * 64 + 63 > q0w) {  // wave-uniform mask skip
#pragma unroll
      for (int n = 0; n < 4; ++n)
#pragma unroll
        for (int r = 0; r < 4; ++r)
          if (j * 64 + n * 16 + lr > q0w + lk * 4 + r) s[n][r] = -__builtin_inff();
    }
    float tm[4];
#pragma unroll
    for (int r = 0; r < 4; ++r) {
      float x = fmaxf(fmaxf(s[0][r], s[1][r]), fmaxf(s[2][r], s[3][r]));
      x = fmaxf(x, __shfl_xor(x, 1));
      x = fmaxf(x, __shfl_xor(x, 2));
      x = fmaxf(x, __shfl_xor(x, 4));
      x = fmaxf(x, __shfl_xor(x, 8));
      tm[r] = x;
    }
    bool need = false;
#pragma unroll
    for (int r = 0; r < 4; ++r) need |= (tm[r] > mi[r] + 64.0f);  // defer-max, raw units
    if (__any(need)) {
#pragma unroll
      for (int r = 0; r < 4; ++r) {
        float mnew = fmaxf(mi[r], tm[r]);
        float alpha = __builtin_amdgcn_exp2f((mi[r] - mnew) * LG);
        mi[r] = mnew;
        li[r] *= alpha;
#pragma unroll
        for (int n = 0; n < 4; ++n) acc[n][r] *= alpha;
      }
    }
    u16* pw = &Pl[w][0][0];
#pragma unroll
    for (int r = 0; r < 4; ++r) {
      int row = lk * 4 + r;
      float mc = -mi[r] * LG;
      float ps = 0.f;
#pragma unroll
      for (int n = 0; n < 4; ++n) {
        float pv = __builtin_amdgcn_exp2f(fmaf(s[n][r], LG, mc));
        ps += pv;
        pw[row * 64 + (((n * 2 + (lr >> 3)) ^ (row & 7)) << 3) + (lr & 7)] = f2bf_rne(pv);
      }
      ps += __shfl_xor(ps, 1);
      ps += __shfl_xor(ps, 2);
      ps += __shfl_xor(ps, 4);
      ps += __shfl_xor(ps, 8);
      li[r] += ps;
    }
  };

  // PV: O += P @ V for the tile currently in Pl[w]
  auto pv = [&](f32x4 (&acc)[4], int cur) {
    const u16* pw = &Pl[w][0][0];
#pragma unroll
    for (int c = 0; c < 2; ++c) {
      bf16x8 pa = *(const bf16x8*)(pw + lr * 64 + (((c * 4 + lk) ^ (lr & 7)) << 3));
#pragma unroll
      for (int n = 0; n < 4; ++n) {
        int dh = n * 16 + lr;
        int phi = (dh & 7) ^ ((dh >> 3) & 7);
        bf16x8 vf = *(const bf16x8*)((const char*)&VT[cur][0][0] + dh * 128 +
                                     ((((c * 4 + lk) ^ phi) & 7) << 4));
        acc[n] = __builtin_amdgcn_mfma_f32_16x16x32_bf16(pa, vf, acc[n], 0, 0, 0);
      }
    }
  };

  // prologue: tile 0 into buffer 0
  stageK(0, 0);
  loadV(0);
  writeV(0);
  __syncthreads();

  for (int j = 0; j < ntB; ++j) {
    const int cur = j & 1;
    const bool more = (j + 1 < ntB);
    if (more) { stageK(j + 1, cur ^ 1); loadV(j + 1); }
    const bool doA = (j < ntA);

    // ---- B side (s live only through this span) ----
    {
      f32x4 s[4] = {};
      qk_one(qfB, s, cur);
      softmax(s, miB, liB, accB, q0B, j);
      pv(accB, cur);
    }
    // ---- A side (Pl WAR ordered by in-order DS ops within each wave) ----
    if (doA) {
      f32x4 s[4] = {};
      qk_one(qfA, s, cur);
      softmax(s, miA, liA, accA, q0A, j);
      pv(accA, cur);
    }

    if (more) writeV(cur ^ 1);
    __syncthreads();
  }

  // ---- epilogue: O = acc / l ----
#pragma unroll
  for (int r = 0; r < 4; ++r) {
    float invB = 1.0f / liB[r];
    size_t orowB = (rowQB + lk * 4 + r) * 1024 + h * 64;
#pragma unroll
    for (int n = 0; n < 4; ++n) O[orowB + n * 16 + lr] = f2bf_rne(accB[n][r] * invB);
    float invA = 1.0f / liA[r];
    size_t orowA = (rowQA + lk * 4 + r) * 1024 + h * 64;
#pragma unroll
    for (int n = 0; n < 4; ++n) O[orowA + n * 16 + lr] = f2bf_rne(accA[n][r] * invA);
  }
}

// ---------- launch ----------
extern "C" void kernel_launch(void* const* d_in, const int* in_sizes, int n_in,
                              void* d_out, int out_size, void* d_ws, size_t ws_size,
                              hipStream_t stream) {
  const float* x = (const float*)d_in[0];
  const float* w_qkv = (const float*)d_in[1];
  const float* b_qkv = (const float*)d_in[2];
  const float* w_out = (const float*)d_in[3];
  const float* b_out = (const float*)d_in[4];
  // d_in[5] = mask: always causal tril, handled analytically.

  char* ws = (char*)d_ws;
  u16* X16 = (u16*)(ws);                  // 16 MB; reused as O16 after GEMM1
  u16* WqkvT = (u16*)(ws + 16777216);     // 6 MB
  u16* WoutT = (u16*)(ws + 23068672);     // 2 MB
  u16* QKVb = (u16*)(ws + 25165824);      // 48 MB
  u16* O16 = X16;

  k_f32_to_bf16<<<8192, 256, 0, stream>>>(x, X16, 8388608 / 4);
  k_transpose_bf16<<<dim3(96, 32), 256, 0, stream>>>(w_qkv, WqkvT, 1024, 3072);
  k_transpose_bf16<<<dim3(32, 32), 256, 0, stream>>>(w_out, WoutT, 1024, 1024);
  k_gemm_bt<1><<<dim3(64, 24), 256, 0, stream>>>(X16, WqkvT, b_qkv, QKVb, 8192, 3072, 1024);
  k_attn<<<dim3(64, 16), 256, 0, stream>>>(QKVb, O16);
  k_gemm_bt<0><<<dim3(64, 8), 256, 0, stream>>>(O16, WoutT, b_out, d_out, 8192, 1024, 1024);
}

// Round 8
// 241.986 us; speedup vs baseline: 2.4814x; 1.8323x over previous
//
#include <hip/hip_runtime.h>
#include <hip/hip_bf16.h>

typedef unsigned short u16;
typedef __bf16 bf16x8 __attribute__((ext_vector_type(8)));
typedef float f32x4 __attribute__((ext_vector_type(4)));
typedef unsigned short u16x8 __attribute__((ext_vector_type(8)));

// ---------- helpers ----------
__device__ __forceinline__ void async_copy16(void* lds, const void* g) {
  __builtin_amdgcn_global_load_lds(
      (const __attribute__((address_space(1))) unsigned int*)g,
      (__attribute__((address_space(3))) unsigned int*)lds, 16, 0, 0);
}

__device__ __forceinline__ u16 f2bf(float f) {
  __hip_bfloat16 h = __float2bfloat16(f);
  u16 u;
  __builtin_memcpy(&u, &h, 2);
  return u;
}

// RNE float->bf16 without NaN handling (inputs known finite): 3 VALU ops.
__device__ __forceinline__ u16 f2bf_rne(float f) {
  unsigned b = __builtin_bit_cast(unsigned, f);
  b += 0x7FFF + ((b >> 16) & 1);
  return (u16)(b >> 16);
}

// ---------- f32 -> bf16 convert (vectorized) ----------
__global__ void k_f32_to_bf16(const float* __restrict__ in, u16* __restrict__ out, int n4) {
  int i = blockIdx.x * blockDim.x + threadIdx.x;
  if (i >= n4) return;
  float4 v = ((const float4*)in)[i];
  ushort4 o;
  o.x = f2bf(v.x); o.y = f2bf(v.y); o.z = f2bf(v.z); o.w = f2bf(v.w);
  ((ushort4*)out)[i] = o;
}

// ---------- transpose RxC f32 -> CxR bf16 ----------
__global__ void k_transpose_bf16(const float* __restrict__ in, u16* __restrict__ out, int R, int C) {
  __shared__ float tile[32][33];
  int bx = blockIdx.x * 32;
  int by = blockIdx.y * 32;
  int tx = threadIdx.x & 31, ty = threadIdx.x >> 5;
  for (int i = ty; i < 32; i += 8) tile[i][tx] = in[(size_t)(by + i) * C + bx + tx];
  __syncthreads();
  for (int i = ty; i < 32; i += 8) out[(size_t)(bx + i) * R + by + tx] = f2bf(tile[tx][i]);
}

// ---------- GEMM: C(MxN) = A(MxK,bf16) @ Bt(NxK,bf16)^T + bias ----------
template <int OUT_BF16>
__global__ __launch_bounds__(256, 2) void k_gemm_bt(
    const u16* __restrict__ A, const u16* __restrict__ Bt,
    const float* __restrict__ bias, void* __restrict__ Cout,
    int M, int N, int K) {
  __shared__ __align__(16) u16 As[128][32];
  __shared__ __align__(16) u16 Bs[128][32];
  const int t = threadIdx.x;
  const int l = t & 63, w = t >> 6;
  const int lr = l & 15, lk = l >> 4;
  const int wr = w >> 1, wc = w & 1;
  const int m0 = blockIdx.x * 128, n0 = blockIdx.y * 128;

  f32x4 acc[4][4] = {};

  for (int k0 = 0; k0 < K; k0 += 32) {
    __syncthreads();
    for (int c = 0; c < 2; ++c) {
      int idx = c * 256 + t;
      int row = idx >> 2, slot = idx & 3;
      int sw = (slot ^ ((row >> 1) & 3)) << 3;
      async_copy16((char*)&As[0][0] + idx * 16, A + (size_t)(m0 + row) * K + k0 + sw);
      async_copy16((char*)&Bs[0][0] + idx * 16, Bt + (size_t)(n0 + row) * K + k0 + sw);
    }
    __syncthreads();
    bf16x8 af[4], bfr[4];
    for (int m = 0; m < 4; ++m) {
      int row = wr * 64 + m * 16 + lr;
      af[m] = *(const bf16x8*)((const char*)&As[0][0] + row * 64 + ((lk ^ ((row >> 1) & 3)) << 4));
    }
    for (int n = 0; n < 4; ++n) {
      int row = wc * 64 + n * 16 + lr;
      bfr[n] = *(const bf16x8*)((const char*)&Bs[0][0] + row * 64 + ((lk ^ ((row >> 1) & 3)) << 4));
    }
    for (int m = 0; m < 4; ++m)
      for (int n = 0; n < 4; ++n)
        acc[m][n] = __builtin_amdgcn_mfma_f32_16x16x32_bf16(af[m], bfr[n], acc[m][n], 0, 0, 0);
  }

  for (int n = 0; n < 4; ++n) {
    int col = n0 + wc * 64 + n * 16 + lr;
    float bv = bias[col];
    for (int m = 0; m < 4; ++m) {
      int rowb = m0 + wr * 64 + m * 16 + lk * 4;
      for (int r = 0; r < 4; ++r) {
        float v = acc[m][n][r] + bv;
        size_t off = (size_t)(rowb + r) * N + col;
        if constexpr (OUT_BF16) ((u16*)Cout)[off] = f2bf(v);
        else ((float*)Cout)[off] = v;
      }
    }
  }
}

// ---------- flash attention, causal, bf16, TWO-PASS ----------
// grid (B*H, 16); block 256 = 4 waves x 16 q-rows. Block (bh,p) runs q-tile
// 31-p then q-tile p as two SEQUENTIAL passes over the KV stream -> 33
// uniform tile-units per block AND only one q-tile's state live at a time
// (~90-110 regs natural vs paired-state 176 which locked occ at 2 waves/SIMD
// in R5 and spilled under any launch_bounds pressure in R4/R6/R7).
// LDS = 40960 B. Spill tripwire: FETCH_SIZE must stay < 100 MB.
__global__ __launch_bounds__(256, 3) void k_attn(
    const u16* __restrict__ QKV,  // (B*S) x 3072 bf16: [Q|K|V]
    u16* __restrict__ O) {        // (B*S) x 1024 bf16
  const int bh = blockIdx.x;  // 0..63 (fastest; same-bh blocks share L2 KV)
  const int p = blockIdx.y;   // 0..15
  const int b = bh >> 4, h = bh & 15;
  const int t = threadIdx.x;
  const int l = t & 63, w = t >> 6;  // 4 waves
  const int lr = l & 15, lk = l >> 4;
  constexpr float LG = 0.18033688f;  // 0.125 * log2(e)

  __shared__ __align__(16) u16 Ks[2][64][64];  // key tiles (src-swizzled), dbuf: 16 KB
  __shared__ __align__(16) u16 VT[2][64][64];  // V^T tiles (two-sided swizzle), dbuf: 16 KB
  __shared__ __align__(16) u16 Pl[4][16][64];  // per-wave P, XOR-swizzled: 8 KB

  const u16* Kb0 = QKV + (size_t)b * 2048 * 3072 + 1024 + h * 64;
  const u16* Vb0 = Kb0 + 1024;

  u16x8 vreg[2];

  auto stageK = [&](int j, int buf) {
#pragma unroll
    for (int c = 0; c < 2; ++c) {
      int gi = c * 256 + t;
      int row = gi >> 3, slot = gi & 7;
      async_copy16((char*)&Ks[buf][0][0] + gi * 16,
                   Kb0 + ((size_t)j * 64 + row) * 3072 + ((slot ^ (row & 7)) << 3));
    }
  };
  auto loadV = [&](int j) {
#pragma unroll
    for (int c = 0; c < 2; ++c) {
      int r = c * 32 + (t >> 3), dh0 = (t & 7) << 3;
      vreg[c] = *(const u16x8*)(Vb0 + ((size_t)j * 64 + r) * 3072 + dh0);
    }
  };
  auto writeV = [&](int buf) {
#pragma unroll
    for (int c = 0; c < 2; ++c) {
      int r = c * 32 + (t >> 3), dh0 = (t & 7) << 3;
#pragma unroll
      for (int jj = 0; jj < 8; ++jj) {
        int dh = dh0 + jj;
        int phi = (dh & 7) ^ ((dh >> 3) & 7);
        VT[buf][dh][((((r >> 3) ^ phi) & 7) << 3) | (r & 7)] = vreg[c][jj];
      }
    }
  };

  // One full flash pass for q-tile qt (KV tiles 0..qt). Only this pass's
  // state is live -> ~half the paired-variant register pressure.
  auto run_tile = [&](int qt) {
    const int nt = qt + 1;
    const int q0w = qt * 64 + w * 16;
    const size_t rowQ = (size_t)b * 2048 + q0w;

    bf16x8 qf[2];
#pragma unroll
    for (int c = 0; c < 2; ++c)
      qf[c] = *(const bf16x8*)(QKV + (rowQ + lr) * 3072 + h * 64 + c * 32 + lk * 8);

    f32x4 acc[4] = {};
    float mi[4], li[4];
#pragma unroll
    for (int r = 0; r < 4; ++r) { mi[r] = -__builtin_inff(); li[r] = 0.f; }

    // prologue: tile 0 into buffer 0
    stageK(0, 0);
    loadV(0);
    writeV(0);
    __syncthreads();

    for (int j = 0; j < nt; ++j) {
      const int cur = j & 1;
      const bool more = (j + 1 < nt);
      if (more) { stageK(j + 1, cur ^ 1); loadV(j + 1); }

      // ---- QK^T ----
      f32x4 s[4] = {};
#pragma unroll
      for (int c = 0; c < 2; ++c)
#pragma unroll
        for (int n = 0; n < 4; ++n) {
          int row = n * 16 + lr;
          bf16x8 kf = *(const bf16x8*)((const char*)&Ks[cur][0][0] + row * 128 +
                                       ((((c * 4 + lk) ^ (row & 7)) & 7) << 4));
          s[n] = __builtin_amdgcn_mfma_f32_16x16x32_bf16(qf[c], kf, s[n], 0, 0, 0);
        }

      // ---- mask + online softmax (exp2-folded, defer-max thr=64 raw) ----
      if (j * 64 + 63 > q0w) {
#pragma unroll
        for (int n = 0; n < 4; ++n)
#pragma unroll
          for (int r = 0; r < 4; ++r)
            if (j * 64 + n * 16 + lr > q0w + lk * 4 + r) s[n][r] = -__builtin_inff();
      }
      float tm[4];
#pragma unroll
      for (int r = 0; r < 4; ++r) {
        float x = fmaxf(fmaxf(s[0][r], s[1][r]), fmaxf(s[2][r], s[3][r]));
        x = fmaxf(x, __shfl_xor(x, 1));
        x = fmaxf(x, __shfl_xor(x, 2));
        x = fmaxf(x, __shfl_xor(x, 4));
        x = fmaxf(x, __shfl_xor(x, 8));
        tm[r] = x;
      }
      bool need = false;
#pragma unroll
      for (int r = 0; r < 4; ++r) need |= (tm[r] > mi[r] + 64.0f);
      if (__any(need)) {
#pragma unroll
        for (int r = 0; r < 4; ++r) {
          float mnew = fmaxf(mi[r], tm[r]);
          float alpha = __builtin_amdgcn_exp2f((mi[r] - mnew) * LG);
          mi[r] = mnew;
          li[r] *= alpha;
#pragma unroll
          for (int n = 0; n < 4; ++n) acc[n][r] *= alpha;
        }
      }
      u16* pw = &Pl[w][0][0];
#pragma unroll
      for (int r = 0; r < 4; ++r) {
        int row = lk * 4 + r;
        float mc = -mi[r] * LG;
        float ps = 0.f;
#pragma unroll
        for (int n = 0; n < 4; ++n) {
          float pv = __builtin_amdgcn_exp2f(fmaf(s[n][r], LG, mc));
          ps += pv;
          pw[row * 64 + (((n * 2 + (lr >> 3)) ^ (row & 7)) << 3) + (lr & 7)] = f2bf_rne(pv);
        }
        ps += __shfl_xor(ps, 1);
        ps += __shfl_xor(ps, 2);
        ps += __shfl_xor(ps, 4);
        ps += __shfl_xor(ps, 8);
        li[r] += ps;
      }

      // ---- PV: acc += P @ V ----
#pragma unroll
      for (int c = 0; c < 2; ++c) {
        bf16x8 pa = *(const bf16x8*)(pw + lr * 64 + (((c * 4 + lk) ^ (lr & 7)) << 3));
#pragma unroll
        for (int n = 0; n < 4; ++n) {
          int dh = n * 16 + lr;
          int phi = (dh & 7) ^ ((dh >> 3) & 7);
          bf16x8 vf = *(const bf16x8*)((const char*)&VT[cur][0][0] + dh * 128 +
                                       ((((c * 4 + lk) ^ phi) & 7) << 4));
          acc[n] = __builtin_amdgcn_mfma_f32_16x16x32_bf16(pa, vf, acc[n], 0, 0, 0);
        }
      }

      if (more) writeV(cur ^ 1);
      __syncthreads();
    }

    // ---- epilogue: O = acc / l (global only; next pass may start LDS writes) ----
#pragma unroll
    for (int r = 0; r < 4; ++r) {
      float inv = 1.0f / li[r];
      size_t orow = (rowQ + lk * 4 + r) * 1024 + h * 64;
#pragma unroll
      for (int n = 0; n < 4; ++n) O[orow + n * 16 + lr] = f2bf_rne(acc[n][r] * inv);
    }
  };

  run_tile(31 - p);  // heavy pass
  run_tile(p);       // light pass
}

// ---------- launch ----------
extern "C" void kernel_launch(void* const* d_in, const int* in_sizes, int n_in,
                              void* d_out, int out_size, void* d_ws, size_t ws_size,
                              hipStream_t stream) {
  const float* x = (const float*)d_in[0];
  const float* w_qkv = (const float*)d_in[1];
  const float* b_qkv = (const float*)d_in[2];
  const float* w_out = (const float*)d_in[3];
  const float* b_out = (const float*)d_in[4];
  // d_in[5] = mask: always causal tril, handled analytically.

  char* ws = (char*)d_ws;
  u16* X16 = (u16*)(ws);                  // 16 MB; reused as O16 after GEMM1
  u16* WqkvT = (u16*)(ws + 16777216);     // 6 MB
  u16* WoutT = (u16*)(ws + 23068672);     // 2 MB
  u16* QKVb = (u16*)(ws + 25165824);      // 48 MB
  u16* O16 = X16;

  k_f32_to_bf16<<<8192, 256, 0, stream>>>(x, X16, 8388608 / 4);
  k_transpose_bf16<<<dim3(96, 32), 256, 0, stream>>>(w_qkv, WqkvT, 1024, 3072);
  k_transpose_bf16<<<dim3(32, 32), 256, 0, stream>>>(w_out, WoutT, 1024, 1024);
  k_gemm_bt<1><<<dim3(64, 24), 256, 0, stream>>>(X16, WqkvT, b_qkv, QKVb, 8192, 3072, 1024);
  k_attn<<<dim3(64, 16), 256, 0, stream>>>(QKVb, O16);
  k_gemm_bt<0><<<dim3(64, 8), 256, 0, stream>>>(O16, WoutT, b_out, d_out, 8192, 1024, 1024);
}

// Round 9
// 235.120 us; speedup vs baseline: 2.5539x; 1.0292x over previous
//
#include <hip/hip_runtime.h>
#include <hip/hip_bf16.h>

typedef unsigned short u16;
typedef __bf16 bf16x8 __attribute__((ext_vector_type(8)));
typedef float f32x4 __attribute__((ext_vector_type(4)));
typedef unsigned short u16x8 __attribute__((ext_vector_type(8)));

// ---------- helpers ----------
__device__ __forceinline__ void async_copy16(void* lds, const void* g) {
  __builtin_amdgcn_global_load_lds(
      (const __attribute__((address_space(1))) unsigned int*)g,
      (__attribute__((address_space(3))) unsigned int*)lds, 16, 0, 0);
}

__device__ __forceinline__ u16 f2bf(float f) {
  __hip_bfloat16 h = __float2bfloat16(f);
  u16 u;
  __builtin_memcpy(&u, &h, 2);
  return u;
}

// RNE float->bf16 without NaN handling (inputs known finite): 3 VALU ops.
__device__ __forceinline__ u16 f2bf_rne(float f) {
  unsigned b = __builtin_bit_cast(unsigned, f);
  b += 0x7FFF + ((b >> 16) & 1);
  return (u16)(b >> 16);
}

// ---------- f32 -> bf16 convert (vectorized) ----------
__global__ void k_f32_to_bf16(const float* __restrict__ in, u16* __restrict__ out, int n4) {
  int i = blockIdx.x * blockDim.x + threadIdx.x;
  if (i >= n4) return;
  float4 v = ((const float4*)in)[i];
  ushort4 o;
  o.x = f2bf(v.x); o.y = f2bf(v.y); o.z = f2bf(v.z); o.w = f2bf(v.w);
  ((ushort4*)out)[i] = o;
}

// ---------- transpose RxC f32 -> CxR bf16 ----------
__global__ void k_transpose_bf16(const float* __restrict__ in, u16* __restrict__ out, int R, int C) {
  __shared__ float tile[32][33];
  int bx = blockIdx.x * 32;
  int by = blockIdx.y * 32;
  int tx = threadIdx.x & 31, ty = threadIdx.x >> 5;
  for (int i = ty; i < 32; i += 8) tile[i][tx] = in[(size_t)(by + i) * C + bx + tx];
  __syncthreads();
  for (int i = ty; i < 32; i += 8) out[(size_t)(bx + i) * R + by + tx] = f2bf(tile[tx][i]);
}

// ---------- GEMM: C(MxN) = A(MxK,bf16) @ Bt(NxK,bf16)^T + bias ----------
template <int OUT_BF16>
__global__ __launch_bounds__(256, 2) void k_gemm_bt(
    const u16* __restrict__ A, const u16* __restrict__ Bt,
    const float* __restrict__ bias, void* __restrict__ Cout,
    int M, int N, int K) {
  __shared__ __align__(16) u16 As[128][32];
  __shared__ __align__(16) u16 Bs[128][32];
  const int t = threadIdx.x;
  const int l = t & 63, w = t >> 6;
  const int lr = l & 15, lk = l >> 4;
  const int wr = w >> 1, wc = w & 1;
  const int m0 = blockIdx.x * 128, n0 = blockIdx.y * 128;

  f32x4 acc[4][4] = {};

  for (int k0 = 0; k0 < K; k0 += 32) {
    __syncthreads();
    for (int c = 0; c < 2; ++c) {
      int idx = c * 256 + t;
      int row = idx >> 2, slot = idx & 3;
      int sw = (slot ^ ((row >> 1) & 3)) << 3;
      async_copy16((char*)&As[0][0] + idx * 16, A + (size_t)(m0 + row) * K + k0 + sw);
      async_copy16((char*)&Bs[0][0] + idx * 16, Bt + (size_t)(n0 + row) * K + k0 + sw);
    }
    __syncthreads();
    bf16x8 af[4], bfr[4];
    for (int m = 0; m < 4; ++m) {
      int row = wr * 64 + m * 16 + lr;
      af[m] = *(const bf16x8*)((const char*)&As[0][0] + row * 64 + ((lk ^ ((row >> 1) & 3)) << 4));
    }
    for (int n = 0; n < 4; ++n) {
      int row = wc * 64 + n * 16 + lr;
      bfr[n] = *(const bf16x8*)((const char*)&Bs[0][0] + row * 64 + ((lk ^ ((row >> 1) & 3)) << 4));
    }
    for (int m = 0; m < 4; ++m)
      for (int n = 0; n < 4; ++n)
        acc[m][n] = __builtin_amdgcn_mfma_f32_16x16x32_bf16(af[m], bfr[n], acc[m][n], 0, 0, 0);
  }

  for (int n = 0; n < 4; ++n) {
    int col = n0 + wc * 64 + n * 16 + lr;
    float bv = bias[col];
    for (int m = 0; m < 4; ++m) {
      int rowb = m0 + wr * 64 + m * 16 + lk * 4;
      for (int r = 0; r < 4; ++r) {
        float v = acc[m][n][r] + bv;
        size_t off = (size_t)(rowb + r) * N + col;
        if constexpr (OUT_BF16) ((u16*)Cout)[off] = f2bf(v);
        else ((float*)Cout)[off] = v;
      }
    }
  }
}

// ---------- flash attention, causal, bf16, TWO-PASS ----------
// grid (B*H, 16); block 256 = 4 waves x 16 q-rows. Block (bh,p) runs q-tile
// 31-p then q-tile p as two SEQUENTIAL passes -> 33 uniform tile-units and
// only one q-tile's state live (~84 arch VGPR + 16 AGPR under min-waves=3,
// R8). LDS = 40960 B x 4 = exactly 160 KiB -> 4 blocks/CU. min-waves=4
// (128-reg budget) now has ~28 regs slack vs the two-pass natural use;
// paired-state spills (R4/R6/R7) don't apply. Grid 1024 = exactly 4/CU ->
// all blocks resident, no tail. Spill tripwire: FETCH_SIZE < 100 MB.
__global__ __launch_bounds__(256, 4) void k_attn(
    const u16* __restrict__ QKV,  // (B*S) x 3072 bf16: [Q|K|V]
    u16* __restrict__ O) {        // (B*S) x 1024 bf16
  const int bh = blockIdx.x;  // 0..63 (fastest; same-bh blocks share L2 KV)
  const int p = blockIdx.y;   // 0..15
  const int b = bh >> 4, h = bh & 15;
  const int t = threadIdx.x;
  const int l = t & 63, w = t >> 6;  // 4 waves
  const int lr = l & 15, lk = l >> 4;
  constexpr float LG = 0.18033688f;  // 0.125 * log2(e)

  __shared__ __align__(16) u16 Ks[2][64][64];  // key tiles (src-swizzled), dbuf: 16 KB
  __shared__ __align__(16) u16 VT[2][64][64];  // V^T tiles (two-sided swizzle), dbuf: 16 KB
  __shared__ __align__(16) u16 Pl[4][16][64];  // per-wave P, XOR-swizzled: 8 KB

  const u16* Kb0 = QKV + (size_t)b * 2048 * 3072 + 1024 + h * 64;
  const u16* Vb0 = Kb0 + 1024;

  u16x8 vreg[2];

  auto stageK = [&](int j, int buf) {
#pragma unroll
    for (int c = 0; c < 2; ++c) {
      int gi = c * 256 + t;
      int row = gi >> 3, slot = gi & 7;
      async_copy16((char*)&Ks[buf][0][0] + gi * 16,
                   Kb0 + ((size_t)j * 64 + row) * 3072 + ((slot ^ (row & 7)) << 3));
    }
  };
  auto loadV = [&](int j) {
#pragma unroll
    for (int c = 0; c < 2; ++c) {
      int r = c * 32 + (t >> 3), dh0 = (t & 7) << 3;
      vreg[c] = *(const u16x8*)(Vb0 + ((size_t)j * 64 + r) * 3072 + dh0);
    }
  };
  auto writeV = [&](int buf) {
#pragma unroll
    for (int c = 0; c < 2; ++c) {
      int r = c * 32 + (t >> 3), dh0 = (t & 7) << 3;
#pragma unroll
      for (int jj = 0; jj < 8; ++jj) {
        int dh = dh0 + jj;
        int phi = (dh & 7) ^ ((dh >> 3) & 7);
        VT[buf][dh][((((r >> 3) ^ phi) & 7) << 3) | (r & 7)] = vreg[c][jj];
      }
    }
  };

  // One full flash pass for q-tile qt (KV tiles 0..qt).
  auto run_tile = [&](int qt) {
    const int nt = qt + 1;
    const int q0w = qt * 64 + w * 16;
    const size_t rowQ = (size_t)b * 2048 + q0w;

    bf16x8 qf[2];
#pragma unroll
    for (int c = 0; c < 2; ++c)
      qf[c] = *(const bf16x8*)(QKV + (rowQ + lr) * 3072 + h * 64 + c * 32 + lk * 8);

    f32x4 acc[4] = {};
    float mi[4], li[4];
#pragma unroll
    for (int r = 0; r < 4; ++r) { mi[r] = -__builtin_inff(); li[r] = 0.f; }

    // prologue: tile 0 into buffer 0
    stageK(0, 0);
    loadV(0);
    writeV(0);
    __syncthreads();

    for (int j = 0; j < nt; ++j) {
      const int cur = j & 1;
      const bool more = (j + 1 < nt);
      if (more) { stageK(j + 1, cur ^ 1); loadV(j + 1); }

      // ---- QK^T ----
      f32x4 s[4] = {};
#pragma unroll
      for (int c = 0; c < 2; ++c)
#pragma unroll
        for (int n = 0; n < 4; ++n) {
          int row = n * 16 + lr;
          bf16x8 kf = *(const bf16x8*)((const char*)&Ks[cur][0][0] + row * 128 +
                                       ((((c * 4 + lk) ^ (row & 7)) & 7) << 4));
          s[n] = __builtin_amdgcn_mfma_f32_16x16x32_bf16(qf[c], kf, s[n], 0, 0, 0);
        }

      // ---- mask + online softmax (exp2-folded, defer-max thr=64 raw) ----
      if (j * 64 + 63 > q0w) {
#pragma unroll
        for (int n = 0; n < 4; ++n)
#pragma unroll
          for (int r = 0; r < 4; ++r)
            if (j * 64 + n * 16 + lr > q0w + lk * 4 + r) s[n][r] = -__builtin_inff();
      }
      float tm[4];
#pragma unroll
      for (int r = 0; r < 4; ++r) {
        float x = fmaxf(fmaxf(s[0][r], s[1][r]), fmaxf(s[2][r], s[3][r]));
        x = fmaxf(x, __shfl_xor(x, 1));
        x = fmaxf(x, __shfl_xor(x, 2));
        x = fmaxf(x, __shfl_xor(x, 4));
        x = fmaxf(x, __shfl_xor(x, 8));
        tm[r] = x;
      }
      bool need = false;
#pragma unroll
      for (int r = 0; r < 4; ++r) need |= (tm[r] > mi[r] + 64.0f);
      if (__any(need)) {
#pragma unroll
        for (int r = 0; r < 4; ++r) {
          float mnew = fmaxf(mi[r], tm[r]);
          float alpha = __builtin_amdgcn_exp2f((mi[r] - mnew) * LG);
          mi[r] = mnew;
          li[r] *= alpha;
#pragma unroll
          for (int n = 0; n < 4; ++n) acc[n][r] *= alpha;
        }
      }
      u16* pw = &Pl[w][0][0];
#pragma unroll
      for (int r = 0; r < 4; ++r) {
        int row = lk * 4 + r;
        float mc = -mi[r] * LG;
        float ps = 0.f;
#pragma unroll
        for (int n = 0; n < 4; ++n) {
          float pv = __builtin_amdgcn_exp2f(fmaf(s[n][r], LG, mc));
          ps += pv;
          pw[row * 64 + (((n * 2 + (lr >> 3)) ^ (row & 7)) << 3) + (lr & 7)] = f2bf_rne(pv);
        }
        ps += __shfl_xor(ps, 1);
        ps += __shfl_xor(ps, 2);
        ps += __shfl_xor(ps, 4);
        ps += __shfl_xor(ps, 8);
        li[r] += ps;
      }

      // ---- PV: acc += P @ V ----
#pragma unroll
      for (int c = 0; c < 2; ++c) {
        bf16x8 pa = *(const bf16x8*)(pw + lr * 64 + (((c * 4 + lk) ^ (lr & 7)) << 3));
#pragma unroll
        for (int n = 0; n < 4; ++n) {
          int dh = n * 16 + lr;
          int phi = (dh & 7) ^ ((dh >> 3) & 7);
          bf16x8 vf = *(const bf16x8*)((const char*)&VT[cur][0][0] + dh * 128 +
                                       ((((c * 4 + lk) ^ phi) & 7) << 4));
          acc[n] = __builtin_amdgcn_mfma_f32_16x16x32_bf16(pa, vf, acc[n], 0, 0, 0);
        }
      }

      if (more) writeV(cur ^ 1);
      __syncthreads();
    }

    // ---- epilogue: O = acc / l ----
#pragma unroll
    for (int r = 0; r < 4; ++r) {
      float inv = 1.0f / li[r];
      size_t orow = (rowQ + lk * 4 + r) * 1024 + h * 64;
#pragma unroll
      for (int n = 0; n < 4; ++n) O[orow + n * 16 + lr] = f2bf_rne(acc[n][r] * inv);
    }
  };

  run_tile(31 - p);  // heavy pass
  run_tile(p);       // light pass
}

// ---------- launch ----------
extern "C" void kernel_launch(void* const* d_in, const int* in_sizes, int n_in,
                              void* d_out, int out_size, void* d_ws, size_t ws_size,
                              hipStream_t stream) {
  const float* x = (const float*)d_in[0];
  const float* w_qkv = (const float*)d_in[1];
  const float* b_qkv = (const float*)d_in[2];
  const float* w_out = (const float*)d_in[3];
  const float* b_out = (const float*)d_in[4];
  // d_in[5] = mask: always causal tril, handled analytically.

  char* ws = (char*)d_ws;
  u16* X16 = (u16*)(ws);                  // 16 MB; reused as O16 after GEMM1
  u16* WqkvT = (u16*)(ws + 16777216);     // 6 MB
  u16* WoutT = (u16*)(ws + 23068672);     // 2 MB
  u16* QKVb = (u16*)(ws + 25165824);      // 48 MB
  u16* O16 = X16;

  k_f32_to_bf16<<<8192, 256, 0, stream>>>(x, X16, 8388608 / 4);
  k_transpose_bf16<<<dim3(96, 32), 256, 0, stream>>>(w_qkv, WqkvT, 1024, 3072);
  k_transpose_bf16<<<dim3(32, 32), 256, 0, stream>>>(w_out, WoutT, 1024, 1024);
  k_gemm_bt<1><<<dim3(64, 24), 256, 0, stream>>>(X16, WqkvT, b_qkv, QKVb, 8192, 3072, 1024);
  k_attn<<<dim3(64, 16), 256, 0, stream>>>(QKVb, O16);
  k_gemm_bt<0><<<dim3(64, 8), 256, 0, stream>>>(O16, WoutT, b_out, d_out, 8192, 1024, 1024);
}

// Round 10
// 188.271 us; speedup vs baseline: 3.1894x; 1.2488x over previous
//
#include <hip/hip_runtime.h>
#include <hip/hip_bf16.h>

typedef unsigned short u16;
typedef __bf16 bf16x8 __attribute__((ext_vector_type(8)));
typedef float f32x4 __attribute__((ext_vector_type(4)));
typedef unsigned short u16x8 __attribute__((ext_vector_type(8)));

// ---------- helpers ----------
__device__ __forceinline__ void async_copy16(void* lds, const void* g) {
  __builtin_amdgcn_global_load_lds(
      (const __attribute__((address_space(1))) unsigned int*)g,
      (__attribute__((address_space(3))) unsigned int*)lds, 16, 0, 0);
}

__device__ __forceinline__ u16 f2bf(float f) {
  __hip_bfloat16 h = __float2bfloat16(f);
  u16 u;
  __builtin_memcpy(&u, &h, 2);
  return u;
}

// RNE float->bf16 without NaN handling (inputs known finite): 3 VALU ops.
__device__ __forceinline__ u16 f2bf_rne(float f) {
  unsigned b = __builtin_bit_cast(unsigned, f);
  b += 0x7FFF + ((b >> 16) & 1);
  return (u16)(b >> 16);
}

// pack two f32 -> one u32 of 2 bf16 (low = a, high = b); no builtin on gfx950.
__device__ __forceinline__ unsigned cvt_pk_bf16(float a, float b) {
  unsigned r;
  asm("v_cvt_pk_bf16_f32 %0, %1, %2" : "=v"(r) : "v"(a), "v"(b));
  return r;
}

// ---------- f32 -> bf16 convert (vectorized) ----------
__global__ void k_f32_to_bf16(const float* __restrict__ in, u16* __restrict__ out, int n4) {
  int i = blockIdx.x * blockDim.x + threadIdx.x;
  if (i >= n4) return;
  float4 v = ((const float4*)in)[i];
  ushort4 o;
  o.x = f2bf(v.x); o.y = f2bf(v.y); o.z = f2bf(v.z); o.w = f2bf(v.w);
  ((ushort4*)out)[i] = o;
}

// ---------- transpose RxC f32 -> CxR bf16 ----------
__global__ void k_transpose_bf16(const float* __restrict__ in, u16* __restrict__ out, int R, int C) {
  __shared__ float tile[32][33];
  int bx = blockIdx.x * 32;
  int by = blockIdx.y * 32;
  int tx = threadIdx.x & 31, ty = threadIdx.x >> 5;
  for (int i = ty; i < 32; i += 8) tile[i][tx] = in[(size_t)(by + i) * C + bx + tx];
  __syncthreads();
  for (int i = ty; i < 32; i += 8) out[(size_t)(bx + i) * R + by + tx] = f2bf(tile[tx][i]);
}

// ---------- GEMM: C(MxN) = A(MxK,bf16) @ Bt(NxK,bf16)^T + bias ----------
template <int OUT_BF16>
__global__ __launch_bounds__(256, 2) void k_gemm_bt(
    const u16* __restrict__ A, const u16* __restrict__ Bt,
    const float* __restrict__ bias, void* __restrict__ Cout,
    int M, int N, int K) {
  __shared__ __align__(16) u16 As[128][32];
  __shared__ __align__(16) u16 Bs[128][32];
  const int t = threadIdx.x;
  const int l = t & 63, w = t >> 6;
  const int lr = l & 15, lk = l >> 4;
  const int wr = w >> 1, wc = w & 1;
  const int m0 = blockIdx.x * 128, n0 = blockIdx.y * 128;

  f32x4 acc[4][4] = {};

  for (int k0 = 0; k0 < K; k0 += 32) {
    __syncthreads();
    for (int c = 0; c < 2; ++c) {
      int idx = c * 256 + t;
      int row = idx >> 2, slot = idx & 3;
      int sw = (slot ^ ((row >> 1) & 3)) << 3;
      async_copy16((char*)&As[0][0] + idx * 16, A + (size_t)(m0 + row) * K + k0 + sw);
      async_copy16((char*)&Bs[0][0] + idx * 16, Bt + (size_t)(n0 + row) * K + k0 + sw);
    }
    __syncthreads();
    bf16x8 af[4], bfr[4];
    for (int m = 0; m < 4; ++m) {
      int row = wr * 64 + m * 16 + lr;
      af[m] = *(const bf16x8*)((const char*)&As[0][0] + row * 64 + ((lk ^ ((row >> 1) & 3)) << 4));
    }
    for (int n = 0; n < 4; ++n) {
      int row = wc * 64 + n * 16 + lr;
      bfr[n] = *(const bf16x8*)((const char*)&Bs[0][0] + row * 64 + ((lk ^ ((row >> 1) & 3)) << 4));
    }
    for (int m = 0; m < 4; ++m)
      for (int n = 0; n < 4; ++n)
        acc[m][n] = __builtin_amdgcn_mfma_f32_16x16x32_bf16(af[m], bfr[n], acc[m][n], 0, 0, 0);
  }

  for (int n = 0; n < 4; ++n) {
    int col = n0 + wc * 64 + n * 16 + lr;
    float bv = bias[col];
    for (int m = 0; m < 4; ++m) {
      int rowb = m0 + wr * 64 + m * 16 + lk * 4;
      for (int r = 0; r < 4; ++r) {
        float v = acc[m][n][r] + bv;
        size_t off = (size_t)(rowb + r) * N + col;
        if constexpr (OUT_BF16) ((u16*)Cout)[off] = f2bf(v);
        else ((float*)Cout)[off] = v;
      }
    }
  }
}

// ---------- flash attention, causal, bf16, TWO-PASS + swapped-QK softmax ----
// grid (B*H, 16); block 256 = 4 waves x 16 q-rows. Block (bh,p) runs q-tile
// 31-p then p sequentially (33 uniform tile-units, one q-tile state live).
// SWAPPED QK: s = mfma(K, Q) -> S^T; lane (lr,lk) holds S[k=n*16+lk*4+r][q=lr]
// => row softmax is 15 local fmax + 2 shuffles (xor16/32) instead of 4x8
// shuffles; P packed via v_cvt_pk_bf16_f32 into 4 ds_write_b64. mi/li are
// per-lane scalars (q=lr); acc rows are q=lk*4+r so rescale/epilogue fetch
// alpha/li via 4 bpermutes (rescale is rare under defer-max thr=64).
// LDS = 40960 B x 4 = 160 KiB -> 4 blocks/CU. FETCH tripwire < 100 MB.
__global__ __launch_bounds__(256, 4) void k_attn(
    const u16* __restrict__ QKV,  // (B*S) x 3072 bf16: [Q|K|V]
    u16* __restrict__ O) {        // (B*S) x 1024 bf16
  const int bh = blockIdx.x;  // 0..63 (fastest; same-bh blocks share L2 KV)
  const int p = blockIdx.y;   // 0..15
  const int b = bh >> 4, h = bh & 15;
  const int t = threadIdx.x;
  const int l = t & 63, w = t >> 6;  // 4 waves
  const int lr = l & 15, lk = l >> 4;
  constexpr float LG = 0.18033688f;  // 0.125 * log2(e)

  __shared__ __align__(16) u16 Ks[2][64][64];  // key tiles (src-swizzled), dbuf: 16 KB
  __shared__ __align__(16) u16 VT[2][64][64];  // V^T tiles (two-sided swizzle), dbuf: 16 KB
  __shared__ __align__(16) u16 Pl[4][16][64];  // per-wave P[q][k], kc ^= q&7: 8 KB

  const u16* Kb0 = QKV + (size_t)b * 2048 * 3072 + 1024 + h * 64;
  const u16* Vb0 = Kb0 + 1024;

  u16x8 vreg[2];

  auto stageK = [&](int j, int buf) {
#pragma unroll
    for (int c = 0; c < 2; ++c) {
      int gi = c * 256 + t;
      int row = gi >> 3, slot = gi & 7;
      async_copy16((char*)&Ks[buf][0][0] + gi * 16,
                   Kb0 + ((size_t)j * 64 + row) * 3072 + ((slot ^ (row & 7)) << 3));
    }
  };
  auto loadV = [&](int j) {
#pragma unroll
    for (int c = 0; c < 2; ++c) {
      int r = c * 32 + (t >> 3), dh0 = (t & 7) << 3;
      vreg[c] = *(const u16x8*)(Vb0 + ((size_t)j * 64 + r) * 3072 + dh0);
    }
  };
  auto writeV = [&](int buf) {
#pragma unroll
    for (int c = 0; c < 2; ++c) {
      int r = c * 32 + (t >> 3), dh0 = (t & 7) << 3;
#pragma unroll
      for (int jj = 0; jj < 8; ++jj) {
        int dh = dh0 + jj;
        int phi = (dh & 7) ^ ((dh >> 3) & 7);
        VT[buf][dh][((((r >> 3) ^ phi) & 7) << 3) | (r & 7)] = vreg[c][jj];
      }
    }
  };

  // One full flash pass for q-tile qt (KV tiles 0..qt).
  auto run_tile = [&](int qt) {
    const int nt = qt + 1;
    const int q0w = qt * 64 + w * 16;
    const size_t rowQ = (size_t)b * 2048 + q0w;

    bf16x8 qf[2];
#pragma unroll
    for (int c = 0; c < 2; ++c)
      qf[c] = *(const bf16x8*)(QKV + (rowQ + lr) * 3072 + h * 64 + c * 32 + lk * 8);

    f32x4 acc[4] = {};
    float mi = -__builtin_inff(), li = 0.f;  // per-lane: q = lr

    // prologue: tile 0 into buffer 0
    stageK(0, 0);
    loadV(0);
    writeV(0);
    __syncthreads();

    for (int j = 0; j < nt; ++j) {
      const int cur = j & 1;
      const bool more = (j + 1 < nt);
      if (more) { stageK(j + 1, cur ^ 1); loadV(j + 1); }

      // ---- S^T = K @ Q^T (swapped): s[n][r] = S[k=n*16+lk*4+r][q=lr] ----
      f32x4 s[4] = {};
#pragma unroll
      for (int c = 0; c < 2; ++c)
#pragma unroll
        for (int n = 0; n < 4; ++n) {
          int row = n * 16 + lr;
          bf16x8 kf = *(const bf16x8*)((const char*)&Ks[cur][0][0] + row * 128 +
                                       ((((c * 4 + lk) ^ (row & 7)) & 7) << 4));
          s[n] = __builtin_amdgcn_mfma_f32_16x16x32_bf16(kf, qf[c], s[n], 0, 0, 0);
        }

      // ---- causal mask: k = j*64+n*16+lk*4+r vs q = q0w+lr ----
      if (j * 64 + 63 > q0w) {
        const int kb = j * 64 + lk * 4;
        const int qq = q0w + lr;
#pragma unroll
        for (int n = 0; n < 4; ++n)
#pragma unroll
          for (int r = 0; r < 4; ++r)
            if (kb + n * 16 + r > qq) s[n][r] = -__builtin_inff();
      }

      // ---- row max: 15 local fmax + 2 shuffles ----
      float tm;
      {
        float m0 = fmaxf(fmaxf(s[0][0], s[0][1]), fmaxf(s[0][2], s[0][3]));
        float m1 = fmaxf(fmaxf(s[1][0], s[1][1]), fmaxf(s[1][2], s[1][3]));
        float m2 = fmaxf(fmaxf(s[2][0], s[2][1]), fmaxf(s[2][2], s[2][3]));
        float m3 = fmaxf(fmaxf(s[3][0], s[3][1]), fmaxf(s[3][2], s[3][3]));
        tm = fmaxf(fmaxf(m0, m1), fmaxf(m2, m3));
        tm = fmaxf(tm, __shfl_xor(tm, 16));
        tm = fmaxf(tm, __shfl_xor(tm, 32));
      }
      // ---- defer-max rescale (raw thr = 64) ----
      if (__any(tm > mi + 64.0f)) {
        float mnew = fmaxf(mi, tm);
        float alpha = __builtin_amdgcn_exp2f((mi - mnew) * LG);
        mi = mnew;
        li *= alpha;
        float a0 = __shfl(alpha, lk * 4 + 0);
        float a1 = __shfl(alpha, lk * 4 + 1);
        float a2 = __shfl(alpha, lk * 4 + 2);
        float a3 = __shfl(alpha, lk * 4 + 3);
#pragma unroll
        for (int n = 0; n < 4; ++n) {
          acc[n][0] *= a0; acc[n][1] *= a1; acc[n][2] *= a2; acc[n][3] *= a3;
        }
      }

      // ---- P = exp2(fma(s,LG,mc)); pack pairs; 4x ds_write_b64 ----
      u16* pw = &Pl[w][0][0];
      {
        const float mc = -mi * LG;
        float ps = 0.f;
#pragma unroll
        for (int n = 0; n < 4; ++n) {
          float p0 = __builtin_amdgcn_exp2f(fmaf(s[n][0], LG, mc));
          float p1 = __builtin_amdgcn_exp2f(fmaf(s[n][1], LG, mc));
          float p2 = __builtin_amdgcn_exp2f(fmaf(s[n][2], LG, mc));
          float p3 = __builtin_amdgcn_exp2f(fmaf(s[n][3], LG, mc));
          ps += (p0 + p1) + (p2 + p3);
          unsigned w0 = cvt_pk_bf16(p0, p1);
          unsigned w1 = cvt_pk_bf16(p2, p3);
          int kc = (n * 2 + (lk >> 1)) ^ (lr & 7);  // 8-elem chunk of k
          *(uint2*)(pw + lr * 64 + kc * 8 + (lk & 1) * 4) = make_uint2(w0, w1);
        }
        ps += __shfl_xor(ps, 16);
        ps += __shfl_xor(ps, 32);
        li += ps;
      }

      // ---- PV: acc += P @ V ----
#pragma unroll
      for (int c = 0; c < 2; ++c) {
        bf16x8 pa = *(const bf16x8*)(pw + lr * 64 + (((c * 4 + lk) ^ (lr & 7)) << 3));
#pragma unroll
        for (int n = 0; n < 4; ++n) {
          int dh = n * 16 + lr;
          int phi = (dh & 7) ^ ((dh >> 3) & 7);
          bf16x8 vf = *(const bf16x8*)((const char*)&VT[cur][0][0] + dh * 128 +
                                       ((((c * 4 + lk) ^ phi) & 7) << 4));
          acc[n] = __builtin_amdgcn_mfma_f32_16x16x32_bf16(pa, vf, acc[n], 0, 0, 0);
        }
      }

      if (more) writeV(cur ^ 1);
      __syncthreads();
    }

    // ---- epilogue: O = acc / l (li lives in lane q=lr; acc rows q=lk*4+r) ----
    float l0 = __shfl(li, lk * 4 + 0);
    float l1 = __shfl(li, lk * 4 + 1);
    float l2 = __shfl(li, lk * 4 + 2);
    float l3 = __shfl(li, lk * 4 + 3);
    float inv[4] = {1.0f / l0, 1.0f / l1, 1.0f / l2, 1.0f / l3};
#pragma unroll
    for (int r = 0; r < 4; ++r) {
      size_t orow = (rowQ + lk * 4 + r) * 1024 + h * 64;
#pragma unroll
      for (int n = 0; n < 4; ++n) O[orow + n * 16 + lr] = f2bf_rne(acc[n][r] * inv[r]);
    }
  };

  run_tile(31 - p);  // heavy pass
  run_tile(p);       // light pass
}

// ---------- launch ----------
extern "C" void kernel_launch(void* const* d_in, const int* in_sizes, int n_in,
                              void* d_out, int out_size, void* d_ws, size_t ws_size,
                              hipStream_t stream) {
  const float* x = (const float*)d_in[0];
  const float* w_qkv = (const float*)d_in[1];
  const float* b_qkv = (const float*)d_in[2];
  const float* w_out = (const float*)d_in[3];
  const float* b_out = (const float*)d_in[4];
  // d_in[5] = mask: always causal tril, handled analytically.

  char* ws = (char*)d_ws;
  u16* X16 = (u16*)(ws);                  // 16 MB; reused as O16 after GEMM1
  u16* WqkvT = (u16*)(ws + 16777216);     // 6 MB
  u16* WoutT = (u16*)(ws + 23068672);     // 2 MB
  u16* QKVb = (u16*)(ws + 25165824);      // 48 MB
  u16* O16 = X16;

  k_f32_to_bf16<<<8192, 256, 0, stream>>>(x, X16, 8388608 / 4);
  k_transpose_bf16<<<dim3(96, 32), 256, 0, stream>>>(w_qkv, WqkvT, 1024, 3072);
  k_transpose_bf16<<<dim3(32, 32), 256, 0, stream>>>(w_out, WoutT, 1024, 1024);
  k_gemm_bt<1><<<dim3(64, 24), 256, 0, stream>>>(X16, WqkvT, b_qkv, QKVb, 8192, 3072, 1024);
  k_attn<<<dim3(64, 16), 256, 0, stream>>>(QKVb, O16);
  k_gemm_bt<0><<<dim3(64, 8), 256, 0, stream>>>(O16, WoutT, b_out, d_out, 8192, 1024, 1024);
}

// Round 11
// 185.739 us; speedup vs baseline: 3.2329x; 1.0136x over previous
//
#include <hip/hip_runtime.h>
#include <hip/hip_bf16.h>

typedef unsigned short u16;
typedef __bf16 bf16x8 __attribute__((ext_vector_type(8)));
typedef float f32x4 __attribute__((ext_vector_type(4)));
typedef unsigned short u16x8 __attribute__((ext_vector_type(8)));

// ---------- helpers ----------
__device__ __forceinline__ void async_copy16(void* lds, const void* g) {
  __builtin_amdgcn_global_load_lds(
      (const __attribute__((address_space(1))) unsigned int*)g,
      (__attribute__((address_space(3))) unsigned int*)lds, 16, 0, 0);
}

__device__ __forceinline__ u16 f2bf(float f) {
  __hip_bfloat16 h = __float2bfloat16(f);
  u16 u;
  __builtin_memcpy(&u, &h, 2);
  return u;
}

// RNE float->bf16 without NaN handling (inputs known finite): 3 VALU ops.
__device__ __forceinline__ u16 f2bf_rne(float f) {
  unsigned b = __builtin_bit_cast(unsigned, f);
  b += 0x7FFF + ((b >> 16) & 1);
  return (u16)(b >> 16);
}

// pack two f32 -> one u32 of 2 bf16 (low = a, high = b); no builtin on gfx950.
__device__ __forceinline__ unsigned cvt_pk_bf16(float a, float b) {
  unsigned r;
  asm("v_cvt_pk_bf16_f32 %0, %1, %2" : "=v"(r) : "v"(a), "v"(b));
  return r;
}

// ---------- f32 -> bf16 convert (vectorized) ----------
__global__ void k_f32_to_bf16(const float* __restrict__ in, u16* __restrict__ out, int n4) {
  int i = blockIdx.x * blockDim.x + threadIdx.x;
  if (i >= n4) return;
  float4 v = ((const float4*)in)[i];
  ushort4 o;
  o.x = f2bf(v.x); o.y = f2bf(v.y); o.z = f2bf(v.z); o.w = f2bf(v.w);
  ((ushort4*)out)[i] = o;
}

// ---------- transpose RxC f32 -> CxR bf16 ----------
__global__ void k_transpose_bf16(const float* __restrict__ in, u16* __restrict__ out, int R, int C) {
  __shared__ float tile[32][33];
  int bx = blockIdx.x * 32;
  int by = blockIdx.y * 32;
  int tx = threadIdx.x & 31, ty = threadIdx.x >> 5;
  for (int i = ty; i < 32; i += 8) tile[i][tx] = in[(size_t)(by + i) * C + bx + tx];
  __syncthreads();
  for (int i = ty; i < 32; i += 8) out[(size_t)(bx + i) * R + by + tx] = f2bf(tile[tx][i]);
}

// ---------- GEMM: C(MxN) = A(MxK,bf16) @ Bt(NxK,bf16)^T + bias ----------
template <int OUT_BF16>
__global__ __launch_bounds__(256, 2) void k_gemm_bt(
    const u16* __restrict__ A, const u16* __restrict__ Bt,
    const float* __restrict__ bias, void* __restrict__ Cout,
    int M, int N, int K) {
  __shared__ __align__(16) u16 As[128][32];
  __shared__ __align__(16) u16 Bs[128][32];
  const int t = threadIdx.x;
  const int l = t & 63, w = t >> 6;
  const int lr = l & 15, lk = l >> 4;
  const int wr = w >> 1, wc = w & 1;
  const int m0 = blockIdx.x * 128, n0 = blockIdx.y * 128;

  f32x4 acc[4][4] = {};

  for (int k0 = 0; k0 < K; k0 += 32) {
    __syncthreads();
    for (int c = 0; c < 2; ++c) {
      int idx = c * 256 + t;
      int row = idx >> 2, slot = idx & 3;
      int sw = (slot ^ ((row >> 1) & 3)) << 3;
      async_copy16((char*)&As[0][0] + idx * 16, A + (size_t)(m0 + row) * K + k0 + sw);
      async_copy16((char*)&Bs[0][0] + idx * 16, Bt + (size_t)(n0 + row) * K + k0 + sw);
    }
    __syncthreads();
    bf16x8 af[4], bfr[4];
    for (int m = 0; m < 4; ++m) {
      int row = wr * 64 + m * 16 + lr;
      af[m] = *(const bf16x8*)((const char*)&As[0][0] + row * 64 + ((lk ^ ((row >> 1) & 3)) << 4));
    }
    for (int n = 0; n < 4; ++n) {
      int row = wc * 64 + n * 16 + lr;
      bfr[n] = *(const bf16x8*)((const char*)&Bs[0][0] + row * 64 + ((lk ^ ((row >> 1) & 3)) << 4));
    }
    for (int m = 0; m < 4; ++m)
      for (int n = 0; n < 4; ++n)
        acc[m][n] = __builtin_amdgcn_mfma_f32_16x16x32_bf16(af[m], bfr[n], acc[m][n], 0, 0, 0);
  }

  for (int n = 0; n < 4; ++n) {
    int col = n0 + wc * 64 + n * 16 + lr;
    float bv = bias[col];
    for (int m = 0; m < 4; ++m) {
      int rowb = m0 + wr * 64 + m * 16 + lk * 4;
      for (int r = 0; r < 4; ++r) {
        float v = acc[m][n][r] + bv;
        size_t off = (size_t)(rowb + r) * N + col;
        if constexpr (OUT_BF16) ((u16*)Cout)[off] = f2bf(v);
        else ((float*)Cout)[off] = v;
      }
    }
  }
}

// ---------- flash attention, causal, bf16 ----------
// TWO-PASS + swapped-QK softmax + 32 q-rows/wave.
// grid (B*H, 8); block 256 = 4 waves x 32 q-rows (2 x 16-row groups) ->
// q-tile of 128 rows. Block (bh,p) runs q-tile 15-p then p sequentially:
// 34 uniform 64-kv tile-units. Per tile-unit each wave issues 32 MFMA while
// K-fragments/V-fragments/staging/barrier are shared across both q-groups
// (2x arithmetic intensity vs R10). SWAPPED QK: s[g] = mfma(K, Q_g) -> lane
// (lr,lk) holds S[k=n*16+lk*4+r][q=g*16+lr]; row softmax = 15 fmax + 2
// shuffles per group; P packed via cvt_pk into 4 ds_write_b64 per group.
// LDS = 49152 B -> 3 blocks/CU cap; grid 512 = 2/CU, all resident.
// launch_bounds(256,3): ~170-reg budget vs ~130 natural (R8-style slack).
// Spill tripwire: FETCH_SIZE < 100 MB.
__global__ __launch_bounds__(256, 3) void k_attn(
    const u16* __restrict__ QKV,  // (B*S) x 3072 bf16: [Q|K|V]
    u16* __restrict__ O) {        // (B*S) x 1024 bf16
  const int bh = blockIdx.x;  // 0..63 (fastest; same-bh blocks share L2 KV)
  const int p = blockIdx.y;   // 0..7
  const int b = bh >> 4, h = bh & 15;
  const int t = threadIdx.x;
  const int l = t & 63, w = t >> 6;  // 4 waves
  const int lr = l & 15, lk = l >> 4;
  constexpr float LG = 0.18033688f;  // 0.125 * log2(e)

  __shared__ __align__(16) u16 Ks[2][64][64];  // key tiles (src-swizzled), dbuf: 16 KB
  __shared__ __align__(16) u16 VT[2][64][64];  // V^T tiles (two-sided swizzle), dbuf: 16 KB
  __shared__ __align__(16) u16 Pl[4][32][64];  // per-wave P[q][k], kc ^= q&7: 16 KB

  const u16* Kb0 = QKV + (size_t)b * 2048 * 3072 + 1024 + h * 64;
  const u16* Vb0 = Kb0 + 1024;

  u16x8 vreg[2];

  auto stageK = [&](int j, int buf) {
#pragma unroll
    for (int c = 0; c < 2; ++c) {
      int gi = c * 256 + t;
      int row = gi >> 3, slot = gi & 7;
      async_copy16((char*)&Ks[buf][0][0] + gi * 16,
                   Kb0 + ((size_t)j * 64 + row) * 3072 + ((slot ^ (row & 7)) << 3));
    }
  };
  auto loadV = [&](int j) {
#pragma unroll
    for (int c = 0; c < 2; ++c) {
      int r = c * 32 + (t >> 3), dh0 = (t & 7) << 3;
      vreg[c] = *(const u16x8*)(Vb0 + ((size_t)j * 64 + r) * 3072 + dh0);
    }
  };
  auto writeV = [&](int buf) {
#pragma unroll
    for (int c = 0; c < 2; ++c) {
      int r = c * 32 + (t >> 3), dh0 = (t & 7) << 3;
#pragma unroll
      for (int jj = 0; jj < 8; ++jj) {
        int dh = dh0 + jj;
        int phi = (dh & 7) ^ ((dh >> 3) & 7);
        VT[buf][dh][((((r >> 3) ^ phi) & 7) << 3) | (r & 7)] = vreg[c][jj];
      }
    }
  };

  // One full flash pass for 128-row q-tile qt (KV tiles 0..2qt+1).
  auto run_tile = [&](int qt) {
    const int nt = 2 * qt + 2;
    const int q0w = qt * 128 + w * 32;  // wave's 32 q-rows: q0w + g*16 + lr
    const size_t rowQ = (size_t)b * 2048 + q0w;

    bf16x8 qf[2][2];  // [group][k-chunk]
#pragma unroll
    for (int g = 0; g < 2; ++g)
#pragma unroll
      for (int c = 0; c < 2; ++c)
        qf[g][c] = *(const bf16x8*)(QKV + (rowQ + g * 16 + lr) * 3072 + h * 64 + c * 32 + lk * 8);

    f32x4 acc[2][4] = {};
    float mi[2], li[2];
#pragma unroll
    for (int g = 0; g < 2; ++g) { mi[g] = -__builtin_inff(); li[g] = 0.f; }

    // prologue: tile 0 into buffer 0
    stageK(0, 0);
    loadV(0);
    writeV(0);
    __syncthreads();

    for (int j = 0; j < nt; ++j) {
      const int cur = j & 1;
      const bool more = (j + 1 < nt);
      if (more) { stageK(j + 1, cur ^ 1); loadV(j + 1); }

      // ---- S^T = K @ Q^T (swapped), kf shared across both q-groups ----
      f32x4 s[2][4] = {};
#pragma unroll
      for (int c = 0; c < 2; ++c)
#pragma unroll
        for (int n = 0; n < 4; ++n) {
          int row = n * 16 + lr;
          bf16x8 kf = *(const bf16x8*)((const char*)&Ks[cur][0][0] + row * 128 +
                                       ((((c * 4 + lk) ^ (row & 7)) & 7) << 4));
          s[0][n] = __builtin_amdgcn_mfma_f32_16x16x32_bf16(kf, qf[0][c], s[0][n], 0, 0, 0);
          s[1][n] = __builtin_amdgcn_mfma_f32_16x16x32_bf16(kf, qf[1][c], s[1][n], 0, 0, 0);
        }

      // ---- causal mask: k = j*64+n*16+lk*4+r vs q = q0w+g*16+lr ----
      if (j * 64 + 63 > q0w) {
        const int kb = j * 64 + lk * 4;
#pragma unroll
        for (int g = 0; g < 2; ++g) {
          const int qq = q0w + g * 16 + lr;
#pragma unroll
          for (int n = 0; n < 4; ++n)
#pragma unroll
            for (int r = 0; r < 4; ++r)
              if (kb + n * 16 + r > qq) s[g][n][r] = -__builtin_inff();
        }
      }

      // ---- row max per group: 15 local fmax + 2 shuffles ----
      float tm[2];
#pragma unroll
      for (int g = 0; g < 2; ++g) {
        float m0 = fmaxf(fmaxf(s[g][0][0], s[g][0][1]), fmaxf(s[g][0][2], s[g][0][3]));
        float m1 = fmaxf(fmaxf(s[g][1][0], s[g][1][1]), fmaxf(s[g][1][2], s[g][1][3]));
        float m2 = fmaxf(fmaxf(s[g][2][0], s[g][2][1]), fmaxf(s[g][2][2], s[g][2][3]));
        float m3 = fmaxf(fmaxf(s[g][3][0], s[g][3][1]), fmaxf(s[g][3][2], s[g][3][3]));
        float x = fmaxf(fmaxf(m0, m1), fmaxf(m2, m3));
        x = fmaxf(x, __shfl_xor(x, 16));
        x = fmaxf(x, __shfl_xor(x, 32));
        tm[g] = x;
      }
      // ---- defer-max rescale (raw thr = 64) ----
      if (__any((tm[0] > mi[0] + 64.0f) || (tm[1] > mi[1] + 64.0f))) {
#pragma unroll
        for (int g = 0; g < 2; ++g) {
          float mnew = fmaxf(mi[g], tm[g]);
          float alpha = __builtin_amdgcn_exp2f((mi[g] - mnew) * LG);
          mi[g] = mnew;
          li[g] *= alpha;
          float a0 = __shfl(alpha, lk * 4 + 0);
          float a1 = __shfl(alpha, lk * 4 + 1);
          float a2 = __shfl(alpha, lk * 4 + 2);
          float a3 = __shfl(alpha, lk * 4 + 3);
#pragma unroll
          for (int n = 0; n < 4; ++n) {
            acc[g][n][0] *= a0; acc[g][n][1] *= a1; acc[g][n][2] *= a2; acc[g][n][3] *= a3;
          }
        }
      }

      // ---- P = exp2(fma(s,LG,mc)); pack pairs; 4x ds_write_b64 per group ----
      u16* pw = &Pl[w][0][0];
#pragma unroll
      for (int g = 0; g < 2; ++g) {
        const float mc = -mi[g] * LG;
        float ps = 0.f;
#pragma unroll
        for (int n = 0; n < 4; ++n) {
          float p0 = __builtin_amdgcn_exp2f(fmaf(s[g][n][0], LG, mc));
          float p1 = __builtin_amdgcn_exp2f(fmaf(s[g][n][1], LG, mc));
          float p2 = __builtin_amdgcn_exp2f(fmaf(s[g][n][2], LG, mc));
          float p3 = __builtin_amdgcn_exp2f(fmaf(s[g][n][3], LG, mc));
          ps += (p0 + p1) + (p2 + p3);
          unsigned w0 = cvt_pk_bf16(p0, p1);
          unsigned w1 = cvt_pk_bf16(p2, p3);
          int kc = (n * 2 + (lk >> 1)) ^ (lr & 7);  // 8-elem chunk of k
          *(uint2*)(pw + (g * 16 + lr) * 64 + kc * 8 + (lk & 1) * 4) = make_uint2(w0, w1);
        }
        ps += __shfl_xor(ps, 16);
        ps += __shfl_xor(ps, 32);
        li[g] += ps;
      }

      // ---- PV: acc += P @ V (vf shared across both q-groups) ----
#pragma unroll
      for (int c = 0; c < 2; ++c) {
        bf16x8 pa0 = *(const bf16x8*)(pw + lr * 64 + (((c * 4 + lk) ^ (lr & 7)) << 3));
        bf16x8 pa1 = *(const bf16x8*)(pw + (16 + lr) * 64 + (((c * 4 + lk) ^ (lr & 7)) << 3));
#pragma unroll
        for (int n = 0; n < 4; ++n) {
          int dh = n * 16 + lr;
          int phi = (dh & 7) ^ ((dh >> 3) & 7);
          bf16x8 vf = *(const bf16x8*)((const char*)&VT[cur][0][0] + dh * 128 +
                                       ((((c * 4 + lk) ^ phi) & 7) << 4));
          acc[0][n] = __builtin_amdgcn_mfma_f32_16x16x32_bf16(pa0, vf, acc[0][n], 0, 0, 0);
          acc[1][n] = __builtin_amdgcn_mfma_f32_16x16x32_bf16(pa1, vf, acc[1][n], 0, 0, 0);
        }
      }

      if (more) writeV(cur ^ 1);
      __syncthreads();
    }

    // ---- epilogue: O = acc / l (li[g] lives in lane q=lr; acc rows q=lk*4+r) ----
#pragma unroll
    for (int g = 0; g < 2; ++g) {
      float l0 = __shfl(li[g], lk * 4 + 0);
      float l1 = __shfl(li[g], lk * 4 + 1);
      float l2 = __shfl(li[g], lk * 4 + 2);
      float l3 = __shfl(li[g], lk * 4 + 3);
      float inv[4] = {1.0f / l0, 1.0f / l1, 1.0f / l2, 1.0f / l3};
#pragma unroll
      for (int r = 0; r < 4; ++r) {
        size_t orow = (rowQ + g * 16 + lk * 4 + r) * 1024 + h * 64;
#pragma unroll
        for (int n = 0; n < 4; ++n) O[orow + n * 16 + lr] = f2bf_rne(acc[g][n][r] * inv[r]);
      }
    }
  };

  run_tile(15 - p);  // heavy pass
  run_tile(p);       // light pass
}

// ---------- launch ----------
extern "C" void kernel_launch(void* const* d_in, const int* in_sizes, int n_in,
                              void* d_out, int out_size, void* d_ws, size_t ws_size,
                              hipStream_t stream) {
  const float* x = (const float*)d_in[0];
  const float* w_qkv = (const float*)d_in[1];
  const float* b_qkv = (const float*)d_in[2];
  const float* w_out = (const float*)d_in[3];
  const float* b_out = (const float*)d_in[4];
  // d_in[5] = mask: always causal tril, handled analytically.

  char* ws = (char*)d_ws;
  u16* X16 = (u16*)(ws);                  // 16 MB; reused as O16 after GEMM1
  u16* WqkvT = (u16*)(ws + 16777216);     // 6 MB
  u16* WoutT = (u16*)(ws + 23068672);     // 2 MB
  u16* QKVb = (u16*)(ws + 25165824);      // 48 MB
  u16* O16 = X16;

  k_f32_to_bf16<<<8192, 256, 0, stream>>>(x, X16, 8388608 / 4);
  k_transpose_bf16<<<dim3(96, 32), 256, 0, stream>>>(w_qkv, WqkvT, 1024, 3072);
  k_transpose_bf16<<<dim3(32, 32), 256, 0, stream>>>(w_out, WoutT, 1024, 1024);
  k_gemm_bt<1><<<dim3(64, 24), 256, 0, stream>>>(X16, WqkvT, b_qkv, QKVb, 8192, 3072, 1024);
  k_attn<<<dim3(64, 8), 256, 0, stream>>>(QKVb, O16);
  k_gemm_bt<0><<<dim3(64, 8), 256, 0, stream>>>(O16, WoutT, b_out, d_out, 8192, 1024, 1024);
}

// Round 12
// 180.989 us; speedup vs baseline: 3.3177x; 1.0262x over previous
//
#include <hip/hip_runtime.h>
#include <hip/hip_bf16.h>

typedef unsigned short u16;
typedef __bf16 bf16x8 __attribute__((ext_vector_type(8)));
typedef float f32x4 __attribute__((ext_vector_type(4)));
typedef unsigned short u16x8 __attribute__((ext_vector_type(8)));

// ---------- helpers ----------
__device__ __forceinline__ void async_copy16(void* lds, const void* g) {
  __builtin_amdgcn_global_load_lds(
      (const __attribute__((address_space(1))) unsigned int*)g,
      (__attribute__((address_space(3))) unsigned int*)lds, 16, 0, 0);
}

__device__ __forceinline__ u16 f2bf(float f) {
  __hip_bfloat16 h = __float2bfloat16(f);
  u16 u;
  __builtin_memcpy(&u, &h, 2);
  return u;
}

// RNE float->bf16 without NaN handling (inputs known finite): 3 VALU ops.
__device__ __forceinline__ u16 f2bf_rne(float f) {
  unsigned b = __builtin_bit_cast(unsigned, f);
  b += 0x7FFF + ((b >> 16) & 1);
  return (u16)(b >> 16);
}

// pack two f32 -> one u32 of 2 bf16 (low = a, high = b); no builtin on gfx950.
__device__ __forceinline__ unsigned cvt_pk_bf16(float a, float b) {
  unsigned r;
  asm("v_cvt_pk_bf16_f32 %0, %1, %2" : "=v"(r) : "v"(a), "v"(b));
  return r;
}

// ---------- f32 -> bf16 convert (vectorized) ----------
__global__ void k_f32_to_bf16(const float* __restrict__ in, u16* __restrict__ out, int n4) {
  int i = blockIdx.x * blockDim.x + threadIdx.x;
  if (i >= n4) return;
  float4 v = ((const float4*)in)[i];
  ushort4 o;
  o.x = f2bf(v.x); o.y = f2bf(v.y); o.z = f2bf(v.z); o.w = f2bf(v.w);
  ((ushort4*)out)[i] = o;
}

// ---------- transpose RxC f32 -> CxR bf16 ----------
__global__ void k_transpose_bf16(const float* __restrict__ in, u16* __restrict__ out, int R, int C) {
  __shared__ float tile[32][33];
  int bx = blockIdx.x * 32;
  int by = blockIdx.y * 32;
  int tx = threadIdx.x & 31, ty = threadIdx.x >> 5;
  for (int i = ty; i < 32; i += 8) tile[i][tx] = in[(size_t)(by + i) * C + bx + tx];
  __syncthreads();
  for (int i = ty; i < 32; i += 8) out[(size_t)(bx + i) * R + by + tx] = f2bf(tile[tx][i]);
}

// ---------- GEMM: C(MxN) = A(MxK,bf16) @ Bt(NxK,bf16)^T + bias ----------
template <int OUT_BF16>
__global__ __launch_bounds__(256, 2) void k_gemm_bt(
    const u16* __restrict__ A, const u16* __restrict__ Bt,
    const float* __restrict__ bias, void* __restrict__ Cout,
    int M, int N, int K) {
  __shared__ __align__(16) u16 As[128][32];
  __shared__ __align__(16) u16 Bs[128][32];
  const int t = threadIdx.x;
  const int l = t & 63, w = t >> 6;
  const int lr = l & 15, lk = l >> 4;
  const int wr = w >> 1, wc = w & 1;
  const int m0 = blockIdx.x * 128, n0 = blockIdx.y * 128;

  f32x4 acc[4][4] = {};

  for (int k0 = 0; k0 < K; k0 += 32) {
    __syncthreads();
    for (int c = 0; c < 2; ++c) {
      int idx = c * 256 + t;
      int row = idx >> 2, slot = idx & 3;
      int sw = (slot ^ ((row >> 1) & 3)) << 3;
      async_copy16((char*)&As[0][0] + idx * 16, A + (size_t)(m0 + row) * K + k0 + sw);
      async_copy16((char*)&Bs[0][0] + idx * 16, Bt + (size_t)(n0 + row) * K + k0 + sw);
    }
    __syncthreads();
    bf16x8 af[4], bfr[4];
    for (int m = 0; m < 4; ++m) {
      int row = wr * 64 + m * 16 + lr;
      af[m] = *(const bf16x8*)((const char*)&As[0][0] + row * 64 + ((lk ^ ((row >> 1) & 3)) << 4));
    }
    for (int n = 0; n < 4; ++n) {
      int row = wc * 64 + n * 16 + lr;
      bfr[n] = *(const bf16x8*)((const char*)&Bs[0][0] + row * 64 + ((lk ^ ((row >> 1) & 3)) << 4));
    }
    for (int m = 0; m < 4; ++m)
      for (int n = 0; n < 4; ++n)
        acc[m][n] = __builtin_amdgcn_mfma_f32_16x16x32_bf16(af[m], bfr[n], acc[m][n], 0, 0, 0);
  }

  for (int n = 0; n < 4; ++n) {
    int col = n0 + wc * 64 + n * 16 + lr;
    float bv = bias[col];
    for (int m = 0; m < 4; ++m) {
      int rowb = m0 + wr * 64 + m * 16 + lk * 4;
      for (int r = 0; r < 4; ++r) {
        float v = acc[m][n][r] + bv;
        size_t off = (size_t)(rowb + r) * N + col;
        if constexpr (OUT_BF16) ((u16*)Cout)[off] = f2bf(v);
        else ((float*)Cout)[off] = v;
      }
    }
  }
}

// ---------- flash attention, causal, bf16 ----------
// TWO-PASS + swapped-QK softmax; 8 waves x 16 q-rows = 128-row q-tile.
// grid (B*H, 8); block 512. Block (bh,p) runs q-tile 15-p then p: 34 uniform
// 64-kv tile-units. Per-wave body = R10's proven lean kernel (64 arch VGPR
// under a 128-reg budget, no spill); 8 waves/block restores 16 waves/CU
// (R11's 4-wave/128-row config dropped to 8 waves/CU and stalled at 84us).
// Staging: each thread does 1 global_load_lds (K) + 1 V-load (8KB tiles,
// 512 threads x 16B). LDS = 48 KB (Ks dbuf 16K + VT dbuf 16K + Pl 8x[16][64]
// 16K); 2 blocks/CU. launch_bounds(512,4) = 128-reg budget (R10-proven).
// Spill tripwire: FETCH_SIZE < 100 MB.
__global__ __launch_bounds__(512, 4) void k_attn(
    const u16* __restrict__ QKV,  // (B*S) x 3072 bf16: [Q|K|V]
    u16* __restrict__ O) {        // (B*S) x 1024 bf16
  const int bh = blockIdx.x;  // 0..63 (fastest; same-bh blocks share L2 KV)
  const int p = blockIdx.y;   // 0..7
  const int b = bh >> 4, h = bh & 15;
  const int t = threadIdx.x;
  const int l = t & 63, w = t >> 6;  // 8 waves
  const int lr = l & 15, lk = l >> 4;
  constexpr float LG = 0.18033688f;  // 0.125 * log2(e)

  __shared__ __align__(16) u16 Ks[2][64][64];  // key tiles (src-swizzled), dbuf: 16 KB
  __shared__ __align__(16) u16 VT[2][64][64];  // V^T tiles (two-sided swizzle), dbuf: 16 KB
  __shared__ __align__(16) u16 Pl[8][16][64];  // per-wave P[q][k], kc ^= q&7: 16 KB

  const u16* Kb0 = QKV + (size_t)b * 2048 * 3072 + 1024 + h * 64;
  const u16* Vb0 = Kb0 + 1024;

  u16x8 vreg;

  auto stageK = [&](int j, int buf) {  // 512 threads cover the 64x64 tile
    int row = t >> 3, slot = t & 7;
    async_copy16((char*)&Ks[buf][0][0] + t * 16,
                 Kb0 + ((size_t)j * 64 + row) * 3072 + ((slot ^ (row & 7)) << 3));
  };
  auto loadV = [&](int j) {
    vreg = *(const u16x8*)(Vb0 + ((size_t)j * 64 + (t >> 3)) * 3072 + ((t & 7) << 3));
  };
  auto writeV = [&](int buf) {
    int r = t >> 3, dh0 = (t & 7) << 3;
#pragma unroll
    for (int jj = 0; jj < 8; ++jj) {
      int dh = dh0 + jj;
      int phi = (dh & 7) ^ ((dh >> 3) & 7);
      VT[buf][dh][((((r >> 3) ^ phi) & 7) << 3) | (r & 7)] = vreg[jj];
    }
  };

  // One full flash pass for 128-row q-tile qt (KV tiles 0..2qt+1).
  // This wave owns 16 q-rows: q = q0w + lr.
  auto run_tile = [&](int qt) {
    const int nt = 2 * qt + 2;
    const int q0w = qt * 128 + w * 16;
    const size_t rowQ = (size_t)b * 2048 + q0w;

    bf16x8 qf[2];
#pragma unroll
    for (int c = 0; c < 2; ++c)
      qf[c] = *(const bf16x8*)(QKV + (rowQ + lr) * 3072 + h * 64 + c * 32 + lk * 8);

    f32x4 acc[4] = {};
    float mi = -__builtin_inff(), li = 0.f;  // per-lane: q = lr

    // prologue: tile 0 into buffer 0
    stageK(0, 0);
    loadV(0);
    writeV(0);
    __syncthreads();

    for (int j = 0; j < nt; ++j) {
      const int cur = j & 1;
      const bool more = (j + 1 < nt);
      if (more) { stageK(j + 1, cur ^ 1); loadV(j + 1); }

      // ---- S^T = K @ Q^T (swapped): s[n][r] = S[k=n*16+lk*4+r][q=lr] ----
      f32x4 s[4] = {};
#pragma unroll
      for (int c = 0; c < 2; ++c)
#pragma unroll
        for (int n = 0; n < 4; ++n) {
          int row = n * 16 + lr;
          bf16x8 kf = *(const bf16x8*)((const char*)&Ks[cur][0][0] + row * 128 +
                                       ((((c * 4 + lk) ^ (row & 7)) & 7) << 4));
          s[n] = __builtin_amdgcn_mfma_f32_16x16x32_bf16(kf, qf[c], s[n], 0, 0, 0);
        }

      // ---- causal mask: k = j*64+n*16+lk*4+r vs q = q0w+lr ----
      if (j * 64 + 63 > q0w) {
        const int kb = j * 64 + lk * 4;
        const int qq = q0w + lr;
#pragma unroll
        for (int n = 0; n < 4; ++n)
#pragma unroll
          for (int r = 0; r < 4; ++r)
            if (kb + n * 16 + r > qq) s[n][r] = -__builtin_inff();
      }

      // ---- row max: 15 local fmax + 2 shuffles ----
      float tm;
      {
        float m0 = fmaxf(fmaxf(s[0][0], s[0][1]), fmaxf(s[0][2], s[0][3]));
        float m1 = fmaxf(fmaxf(s[1][0], s[1][1]), fmaxf(s[1][2], s[1][3]));
        float m2 = fmaxf(fmaxf(s[2][0], s[2][1]), fmaxf(s[2][2], s[2][3]));
        float m3 = fmaxf(fmaxf(s[3][0], s[3][1]), fmaxf(s[3][2], s[3][3]));
        tm = fmaxf(fmaxf(m0, m1), fmaxf(m2, m3));
        tm = fmaxf(tm, __shfl_xor(tm, 16));
        tm = fmaxf(tm, __shfl_xor(tm, 32));
      }
      // ---- defer-max rescale (raw thr = 64) ----
      if (__any(tm > mi + 64.0f)) {
        float mnew = fmaxf(mi, tm);
        float alpha = __builtin_amdgcn_exp2f((mi - mnew) * LG);
        mi = mnew;
        li *= alpha;
        float a0 = __shfl(alpha, lk * 4 + 0);
        float a1 = __shfl(alpha, lk * 4 + 1);
        float a2 = __shfl(alpha, lk * 4 + 2);
        float a3 = __shfl(alpha, lk * 4 + 3);
#pragma unroll
        for (int n = 0; n < 4; ++n) {
          acc[n][0] *= a0; acc[n][1] *= a1; acc[n][2] *= a2; acc[n][3] *= a3;
        }
      }

      // ---- P = exp2(fma(s,LG,mc)); pack pairs; 4x ds_write_b64 ----
      u16* pw = &Pl[w][0][0];
      {
        const float mc = -mi * LG;
        float ps = 0.f;
#pragma unroll
        for (int n = 0; n < 4; ++n) {
          float p0 = __builtin_amdgcn_exp2f(fmaf(s[n][0], LG, mc));
          float p1 = __builtin_amdgcn_exp2f(fmaf(s[n][1], LG, mc));
          float p2 = __builtin_amdgcn_exp2f(fmaf(s[n][2], LG, mc));
          float p3 = __builtin_amdgcn_exp2f(fmaf(s[n][3], LG, mc));
          ps += (p0 + p1) + (p2 + p3);
          unsigned w0 = cvt_pk_bf16(p0, p1);
          unsigned w1 = cvt_pk_bf16(p2, p3);
          int kc = (n * 2 + (lk >> 1)) ^ (lr & 7);  // 8-elem chunk of k
          *(uint2*)(pw + lr * 64 + kc * 8 + (lk & 1) * 4) = make_uint2(w0, w1);
        }
        ps += __shfl_xor(ps, 16);
        ps += __shfl_xor(ps, 32);
        li += ps;
      }

      // ---- PV: acc += P @ V ----
#pragma unroll
      for (int c = 0; c < 2; ++c) {
        bf16x8 pa = *(const bf16x8*)(pw + lr * 64 + (((c * 4 + lk) ^ (lr & 7)) << 3));
#pragma unroll
        for (int n = 0; n < 4; ++n) {
          int dh = n * 16 + lr;
          int phi = (dh & 7) ^ ((dh >> 3) & 7);
          bf16x8 vf = *(const bf16x8*)((const char*)&VT[cur][0][0] + dh * 128 +
                                       ((((c * 4 + lk) ^ phi) & 7) << 4));
          acc[n] = __builtin_amdgcn_mfma_f32_16x16x32_bf16(pa, vf, acc[n], 0, 0, 0);
        }
      }

      if (more) writeV(cur ^ 1);
      __syncthreads();
    }

    // ---- epilogue: O = acc / l (li lives in lane q=lr; acc rows q=lk*4+r) ----
    float l0 = __shfl(li, lk * 4 + 0);
    float l1 = __shfl(li, lk * 4 + 1);
    float l2 = __shfl(li, lk * 4 + 2);
    float l3 = __shfl(li, lk * 4 + 3);
    float inv[4] = {1.0f / l0, 1.0f / l1, 1.0f / l2, 1.0f / l3};
#pragma unroll
    for (int r = 0; r < 4; ++r) {
      size_t orow = (rowQ + lk * 4 + r) * 1024 + h * 64;
#pragma unroll
      for (int n = 0; n < 4; ++n) O[orow + n * 16 + lr] = f2bf_rne(acc[n][r] * inv[r]);
    }
  };

  run_tile(15 - p);  // heavy pass
  run_tile(p);       // light pass
}

// ---------- launch ----------
extern "C" void kernel_launch(void* const* d_in, const int* in_sizes, int n_in,
                              void* d_out, int out_size, void* d_ws, size_t ws_size,
                              hipStream_t stream) {
  const float* x = (const float*)d_in[0];
  const float* w_qkv = (const float*)d_in[1];
  const float* b_qkv = (const float*)d_in[2];
  const float* w_out = (const float*)d_in[3];
  const float* b_out = (const float*)d_in[4];
  // d_in[5] = mask: always causal tril, handled analytically.

  char* ws = (char*)d_ws;
  u16* X16 = (u16*)(ws);                  // 16 MB; reused as O16 after GEMM1
  u16* WqkvT = (u16*)(ws + 16777216);     // 6 MB
  u16* WoutT = (u16*)(ws + 23068672);     // 2 MB
  u16* QKVb = (u16*)(ws + 25165824);      // 48 MB
  u16* O16 = X16;

  k_f32_to_bf16<<<8192, 256, 0, stream>>>(x, X16, 8388608 / 4);
  k_transpose_bf16<<<dim3(96, 32), 256, 0, stream>>>(w_qkv, WqkvT, 1024, 3072);
  k_transpose_bf16<<<dim3(32, 32), 256, 0, stream>>>(w_out, WoutT, 1024, 1024);
  k_gemm_bt<1><<<dim3(64, 24), 256, 0, stream>>>(X16, WqkvT, b_qkv, QKVb, 8192, 3072, 1024);
  k_attn<<<dim3(64, 8), 512, 0, stream>>>(QKVb, O16);
  k_gemm_bt<0><<<dim3(64, 8), 256, 0, stream>>>(O16, WoutT, b_out, d_out, 8192, 1024, 1024);
}

// Round 13
// 179.527 us; speedup vs baseline: 3.3447x; 1.0081x over previous
//
#include <hip/hip_runtime.h>
#include <hip/hip_bf16.h>

typedef unsigned short u16;
typedef __bf16 bf16x8 __attribute__((ext_vector_type(8)));
typedef float f32x4 __attribute__((ext_vector_type(4)));
typedef unsigned short u16x8 __attribute__((ext_vector_type(8)));

// ---------- helpers ----------
__device__ __forceinline__ void async_copy16(void* lds, const void* g) {
  __builtin_amdgcn_global_load_lds(
      (const __attribute__((address_space(1))) unsigned int*)g,
      (__attribute__((address_space(3))) unsigned int*)lds, 16, 0, 0);
}

__device__ __forceinline__ u16 f2bf(float f) {
  __hip_bfloat16 h = __float2bfloat16(f);
  u16 u;
  __builtin_memcpy(&u, &h, 2);
  return u;
}

// RNE float->bf16 without NaN handling (inputs known finite): 3 VALU ops.
__device__ __forceinline__ u16 f2bf_rne(float f) {
  unsigned b = __builtin_bit_cast(unsigned, f);
  b += 0x7FFF + ((b >> 16) & 1);
  return (u16)(b >> 16);
}

// pack two f32 -> one u32 of 2 bf16 (low = a, high = b); no builtin on gfx950.
__device__ __forceinline__ unsigned cvt_pk_bf16(float a, float b) {
  unsigned r;
  asm("v_cvt_pk_bf16_f32 %0, %1, %2" : "=v"(r) : "v"(a), "v"(b));
  return r;
}

// ---------- f32 -> bf16 convert (vectorized) ----------
__global__ void k_f32_to_bf16(const float* __restrict__ in, u16* __restrict__ out, int n4) {
  int i = blockIdx.x * blockDim.x + threadIdx.x;
  if (i >= n4) return;
  float4 v = ((const float4*)in)[i];
  ushort4 o;
  o.x = f2bf(v.x); o.y = f2bf(v.y); o.z = f2bf(v.z); o.w = f2bf(v.w);
  ((ushort4*)out)[i] = o;
}

// ---------- transpose RxC f32 -> CxR bf16 ----------
__global__ void k_transpose_bf16(const float* __restrict__ in, u16* __restrict__ out, int R, int C) {
  __shared__ float tile[32][33];
  int bx = blockIdx.x * 32;
  int by = blockIdx.y * 32;
  int tx = threadIdx.x & 31, ty = threadIdx.x >> 5;
  for (int i = ty; i < 32; i += 8) tile[i][tx] = in[(size_t)(by + i) * C + bx + tx];
  __syncthreads();
  for (int i = ty; i < 32; i += 8) out[(size_t)(bx + i) * R + by + tx] = f2bf(tile[tx][i]);
}

// ---------- GEMM: C(MxN) = A(MxK,bf16) @ Bt(NxK,bf16)^T + bias ----------
template <int OUT_BF16>
__global__ __launch_bounds__(256, 2) void k_gemm_bt(
    const u16* __restrict__ A, const u16* __restrict__ Bt,
    const float* __restrict__ bias, void* __restrict__ Cout,
    int M, int N, int K) {
  __shared__ __align__(16) u16 As[128][32];
  __shared__ __align__(16) u16 Bs[128][32];
  const int t = threadIdx.x;
  const int l = t & 63, w = t >> 6;
  const int lr = l & 15, lk = l >> 4;
  const int wr = w >> 1, wc = w & 1;
  const int m0 = blockIdx.x * 128, n0 = blockIdx.y * 128;

  f32x4 acc[4][4] = {};

  for (int k0 = 0; k0 < K; k0 += 32) {
    __syncthreads();
    for (int c = 0; c < 2; ++c) {
      int idx = c * 256 + t;
      int row = idx >> 2, slot = idx & 3;
      int sw = (slot ^ ((row >> 1) & 3)) << 3;
      async_copy16((char*)&As[0][0] + idx * 16, A + (size_t)(m0 + row) * K + k0 + sw);
      async_copy16((char*)&Bs[0][0] + idx * 16, Bt + (size_t)(n0 + row) * K + k0 + sw);
    }
    __syncthreads();
    bf16x8 af[4], bfr[4];
    for (int m = 0; m < 4; ++m) {
      int row = wr * 64 + m * 16 + lr;
      af[m] = *(const bf16x8*)((const char*)&As[0][0] + row * 64 + ((lk ^ ((row >> 1) & 3)) << 4));
    }
    for (int n = 0; n < 4; ++n) {
      int row = wc * 64 + n * 16 + lr;
      bfr[n] = *(const bf16x8*)((const char*)&Bs[0][0] + row * 64 + ((lk ^ ((row >> 1) & 3)) << 4));
    }
    for (int m = 0; m < 4; ++m)
      for (int n = 0; n < 4; ++n)
        acc[m][n] = __builtin_amdgcn_mfma_f32_16x16x32_bf16(af[m], bfr[n], acc[m][n], 0, 0, 0);
  }

  for (int n = 0; n < 4; ++n) {
    int col = n0 + wc * 64 + n * 16 + lr;
    float bv = bias[col];
    for (int m = 0; m < 4; ++m) {
      int rowb = m0 + wr * 64 + m * 16 + lk * 4;
      for (int r = 0; r < 4; ++r) {
        float v = acc[m][n][r] + bv;
        size_t off = (size_t)(rowb + r) * N + col;
        if constexpr (OUT_BF16) ((u16*)Cout)[off] = f2bf(v);
        else ((float*)Cout)[off] = v;
      }
    }
  }
}

// ---------- flash attention, causal, bf16 ----------
// UN-PAIRED + swapped-QK softmax; 8 waves x 16 q-rows = 128-row q-tile.
// grid (B*H, 16); block 512. Block (bh, y) owns q-tile qt = 15-y (heavy
// blocks dispatch FIRST -> LPT backfill of the causal-imbalance tail).
// 1024 blocks, LDS 48 KB -> 3 blocks/CU resident (24 waves/CU); regs 64
// arch under the proven (512,4) 128-reg budget. R12 lesson: pairing was a
// spill fix (R7) that now CAPS residency at 2 blocks/CU; un-pairing trades
// per-block uniformity for +50% waves/CU. Total staging volume unchanged.
// T5: setprio(1) around MFMA clusters (attn-positive per m191; 3 independent
// blocks/CU give the CU scheduler real phase diversity to arbitrate).
// Spill tripwire: FETCH_SIZE < 100 MB.
__global__ __launch_bounds__(512, 4) void k_attn(
    const u16* __restrict__ QKV,  // (B*S) x 3072 bf16: [Q|K|V]
    u16* __restrict__ O) {        // (B*S) x 1024 bf16
  const int bh = blockIdx.x;  // 0..63 (fastest; same-bh blocks share L2 KV)
  const int qt = 15 - blockIdx.y;  // heavy first
  const int b = bh >> 4, h = bh & 15;
  const int t = threadIdx.x;
  const int l = t & 63, w = t >> 6;  // 8 waves
  const int lr = l & 15, lk = l >> 4;
  constexpr float LG = 0.18033688f;  // 0.125 * log2(e)

  __shared__ __align__(16) u16 Ks[2][64][64];  // key tiles (src-swizzled), dbuf: 16 KB
  __shared__ __align__(16) u16 VT[2][64][64];  // V^T tiles (two-sided swizzle), dbuf: 16 KB
  __shared__ __align__(16) u16 Pl[8][16][64];  // per-wave P[q][k], kc ^= q&7: 16 KB

  const u16* Kb0 = QKV + (size_t)b * 2048 * 3072 + 1024 + h * 64;
  const u16* Vb0 = Kb0 + 1024;

  u16x8 vreg;

  auto stageK = [&](int j, int buf) {  // 512 threads cover the 64x64 tile
    int row = t >> 3, slot = t & 7;
    async_copy16((char*)&Ks[buf][0][0] + t * 16,
                 Kb0 + ((size_t)j * 64 + row) * 3072 + ((slot ^ (row & 7)) << 3));
  };
  auto loadV = [&](int j) {
    vreg = *(const u16x8*)(Vb0 + ((size_t)j * 64 + (t >> 3)) * 3072 + ((t & 7) << 3));
  };
  auto writeV = [&](int buf) {
    int r = t >> 3, dh0 = (t & 7) << 3;
#pragma unroll
    for (int jj = 0; jj < 8; ++jj) {
      int dh = dh0 + jj;
      int phi = (dh & 7) ^ ((dh >> 3) & 7);
      VT[buf][dh][((((r >> 3) ^ phi) & 7) << 3) | (r & 7)] = vreg[jj];
    }
  };

  const int nt = 2 * qt + 2;
  const int q0w = qt * 128 + w * 16;  // this wave's 16 q-rows: q = q0w + lr
  const size_t rowQ = (size_t)b * 2048 + q0w;

  bf16x8 qf[2];
#pragma unroll
  for (int c = 0; c < 2; ++c)
    qf[c] = *(const bf16x8*)(QKV + (rowQ + lr) * 3072 + h * 64 + c * 32 + lk * 8);

  f32x4 acc[4] = {};
  float mi = -__builtin_inff(), li = 0.f;  // per-lane: q = lr

  // prologue: tile 0 into buffer 0
  stageK(0, 0);
  loadV(0);
  writeV(0);
  __syncthreads();

  for (int j = 0; j < nt; ++j) {
    const int cur = j & 1;
    const bool more = (j + 1 < nt);
    if (more) { stageK(j + 1, cur ^ 1); loadV(j + 1); }

    // ---- S^T = K @ Q^T (swapped): s[n][r] = S[k=n*16+lk*4+r][q=lr] ----
    f32x4 s[4] = {};
    __builtin_amdgcn_s_setprio(1);
#pragma unroll
    for (int c = 0; c < 2; ++c)
#pragma unroll
      for (int n = 0; n < 4; ++n) {
        int row = n * 16 + lr;
        bf16x8 kf = *(const bf16x8*)((const char*)&Ks[cur][0][0] + row * 128 +
                                     ((((c * 4 + lk) ^ (row & 7)) & 7) << 4));
        s[n] = __builtin_amdgcn_mfma_f32_16x16x32_bf16(kf, qf[c], s[n], 0, 0, 0);
      }
    __builtin_amdgcn_s_setprio(0);

    // ---- causal mask: k = j*64+n*16+lk*4+r vs q = q0w+lr ----
    if (j * 64 + 63 > q0w) {
      const int kb = j * 64 + lk * 4;
      const int qq = q0w + lr;
#pragma unroll
      for (int n = 0; n < 4; ++n)
#pragma unroll
        for (int r = 0; r < 4; ++r)
          if (kb + n * 16 + r > qq) s[n][r] = -__builtin_inff();
    }

    // ---- row max: 15 local fmax + 2 shuffles ----
    float tm;
    {
      float m0 = fmaxf(fmaxf(s[0][0], s[0][1]), fmaxf(s[0][2], s[0][3]));
      float m1 = fmaxf(fmaxf(s[1][0], s[1][1]), fmaxf(s[1][2], s[1][3]));
      float m2 = fmaxf(fmaxf(s[2][0], s[2][1]), fmaxf(s[2][2], s[2][3]));
      float m3 = fmaxf(fmaxf(s[3][0], s[3][1]), fmaxf(s[3][2], s[3][3]));
      tm = fmaxf(fmaxf(m0, m1), fmaxf(m2, m3));
      tm = fmaxf(tm, __shfl_xor(tm, 16));
      tm = fmaxf(tm, __shfl_xor(tm, 32));
    }
    // ---- defer-max rescale (raw thr = 64) ----
    if (__any(tm > mi + 64.0f)) {
      float mnew = fmaxf(mi, tm);
      float alpha = __builtin_amdgcn_exp2f((mi - mnew) * LG);
      mi = mnew;
      li *= alpha;
      float a0 = __shfl(alpha, lk * 4 + 0);
      float a1 = __shfl(alpha, lk * 4 + 1);
      float a2 = __shfl(alpha, lk * 4 + 2);
      float a3 = __shfl(alpha, lk * 4 + 3);
#pragma unroll
      for (int n = 0; n < 4; ++n) {
        acc[n][0] *= a0; acc[n][1] *= a1; acc[n][2] *= a2; acc[n][3] *= a3;
      }
    }

    // ---- P = exp2(fma(s,LG,mc)); pack pairs; 4x ds_write_b64 ----
    u16* pw = &Pl[w][0][0];
    {
      const float mc = -mi * LG;
      float ps = 0.f;
#pragma unroll
      for (int n = 0; n < 4; ++n) {
        float p0 = __builtin_amdgcn_exp2f(fmaf(s[n][0], LG, mc));
        float p1 = __builtin_amdgcn_exp2f(fmaf(s[n][1], LG, mc));
        float p2 = __builtin_amdgcn_exp2f(fmaf(s[n][2], LG, mc));
        float p3 = __builtin_amdgcn_exp2f(fmaf(s[n][3], LG, mc));
        ps += (p0 + p1) + (p2 + p3);
        unsigned w0 = cvt_pk_bf16(p0, p1);
        unsigned w1 = cvt_pk_bf16(p2, p3);
        int kc = (n * 2 + (lk >> 1)) ^ (lr & 7);  // 8-elem chunk of k
        *(uint2*)(pw + lr * 64 + kc * 8 + (lk & 1) * 4) = make_uint2(w0, w1);
      }
      ps += __shfl_xor(ps, 16);
      ps += __shfl_xor(ps, 32);
      li += ps;
    }

    // ---- PV: acc += P @ V ----
    __builtin_amdgcn_s_setprio(1);
#pragma unroll
    for (int c = 0; c < 2; ++c) {
      bf16x8 pa = *(const bf16x8*)(pw + lr * 64 + (((c * 4 + lk) ^ (lr & 7)) << 3));
#pragma unroll
      for (int n = 0; n < 4; ++n) {
        int dh = n * 16 + lr;
        int phi = (dh & 7) ^ ((dh >> 3) & 7);
        bf16x8 vf = *(const bf16x8*)((const char*)&VT[cur][0][0] + dh * 128 +
                                     ((((c * 4 + lk) ^ phi) & 7) << 4));
        acc[n] = __builtin_amdgcn_mfma_f32_16x16x32_bf16(pa, vf, acc[n], 0, 0, 0);
      }
    }
    __builtin_amdgcn_s_setprio(0);

    if (more) writeV(cur ^ 1);
    __syncthreads();
  }

  // ---- epilogue: O = acc / l (li lives in lane q=lr; acc rows q=lk*4+r) ----
  float l0 = __shfl(li, lk * 4 + 0);
  float l1 = __shfl(li, lk * 4 + 1);
  float l2 = __shfl(li, lk * 4 + 2);
  float l3 = __shfl(li, lk * 4 + 3);
  float inv[4] = {1.0f / l0, 1.0f / l1, 1.0f / l2, 1.0f / l3};
#pragma unroll
  for (int r = 0; r < 4; ++r) {
    size_t orow = (rowQ + lk * 4 + r) * 1024 + h * 64;
#pragma unroll
    for (int n = 0; n < 4; ++n) O[orow + n * 16 + lr] = f2bf_rne(acc[n][r] * inv[r]);
  }
}

// ---------- launch ----------
extern "C" void kernel_launch(void* const* d_in, const int* in_sizes, int n_in,
                              void* d_out, int out_size, void* d_ws, size_t ws_size,
                              hipStream_t stream) {
  const float* x = (const float*)d_in[0];
  const float* w_qkv = (const float*)d_in[1];
  const float* b_qkv = (const float*)d_in[2];
  const float* w_out = (const float*)d_in[3];
  const float* b_out = (const float*)d_in[4];
  // d_in[5] = mask: always causal tril, handled analytically.

  char* ws = (char*)d_ws;
  u16* X16 = (u16*)(ws);                  // 16 MB; reused as O16 after GEMM1
  u16* WqkvT = (u16*)(ws + 16777216);     // 6 MB
  u16* WoutT = (u16*)(ws + 23068672);     // 2 MB
  u16* QKVb = (u16*)(ws + 25165824);      // 48 MB
  u16* O16 = X16;

  k_f32_to_bf16<<<8192, 256, 0, stream>>>(x, X16, 8388608 / 4);
  k_transpose_bf16<<<dim3(96, 32), 256, 0, stream>>>(w_qkv, WqkvT, 1024, 3072);
  k_transpose_bf16<<<dim3(32, 32), 256, 0, stream>>>(w_out, WoutT, 1024, 1024);
  k_gemm_bt<1><<<dim3(64, 24), 256, 0, stream>>>(X16, WqkvT, b_qkv, QKVb, 8192, 3072, 1024);
  k_attn<<<dim3(64, 16), 512, 0, stream>>>(QKVb, O16);
  k_gemm_bt<0><<<dim3(64, 8), 256, 0, stream>>>(O16, WoutT, b_out, d_out, 8192, 1024, 1024);
}